// Round 1
// baseline (2298.630 us; speedup 1.0000x reference)
//
#include <hip/hip_runtime.h>
#include <math.h>

#define S_LEN 2048
#define BATCH 2
#define EMB   1024
#define NH    16
#define DH    64
#define E3    3072
#define FF    4096
#define PP    64

// ---------------- pos-embedding projection + L1 norm ----------------
// pe[b,q,s] = (sum_p pos_w[q,p]*pos_embed[b,p,s] + pos_b[q]) / max(sum_q|.|,eps)
__global__ __launch_bounds__(64) void pe_kernel(
    const float* __restrict__ pos_embed, const float* __restrict__ pos_w,
    const float* __restrict__ pos_b, float* __restrict__ pe)
{
  __shared__ float pw[PP * PP];
  int tid = threadIdx.x;
  for (int i = 0; i < PP; ++i) pw[i * PP + tid] = pos_w[i * PP + tid];
  __syncthreads();
  int s = blockIdx.x * 64 + tid;
  int b = blockIdx.y;
  float acc[PP];
#pragma unroll
  for (int q = 0; q < PP; ++q) acc[q] = pos_b[q];
  for (int p = 0; p < PP; ++p) {
    float x = pos_embed[(size_t)(b * PP + p) * S_LEN + s];
#pragma unroll
    for (int q = 0; q < PP; ++q) acc[q] += pw[q * PP + p] * x;
  }
  float l1 = 0.f;
#pragma unroll
  for (int q = 0; q < PP; ++q) l1 += fabsf(acc[q]);
  float inv = 1.f / fmaxf(l1, 1e-12f);
  for (int q = 0; q < PP; ++q)
    pe[(size_t)(b * PP + q) * S_LEN + s] = acc[q] * inv;
}

// ---------------- pos_sim[b,s,t] = sum_q pe[b,q,s]*pe[b,q,t] ----------------
__global__ __launch_bounds__(256) void possim_kernel(
    const float* __restrict__ pe, float* __restrict__ pos_sim)
{
  int t = blockIdx.x * 256 + threadIdx.x;
  int s = blockIdx.y;
  int b = blockIdx.z;
  const float* pb = pe + (size_t)b * PP * S_LEN;
  float a = 0.f;
#pragma unroll
  for (int q = 0; q < PP; ++q)
    a += pb[q * S_LEN + s] * pb[q * S_LEN + t];
  pos_sim[((size_t)(b * S_LEN + s)) * S_LEN + t] = a;
}

// ---------------- fp32 SGEMM: C[M,N] = A[M,K] @ W[N,K]^T + bias, opt relu ----
#define GBM 128
#define GBN 128
#define GBK 8
__global__ __launch_bounds__(256) void gemm_kernel(
    const float* __restrict__ A, const float* __restrict__ W,
    const float* __restrict__ bias, float* __restrict__ C,
    int M, int N, int K, int relu)
{
  __shared__ float As[GBK][GBM];
  __shared__ float Bs[GBK][GBN];
  int tid = threadIdx.x;
  int bn = blockIdx.x * GBN;
  int bm = blockIdx.y * GBM;
  int tx = tid & 15, ty = tid >> 4;
  int ar = tid >> 1;
  int ac = (tid & 1) * 4;
  const float* Ap = A + (size_t)(bm + ar) * K + ac;
  const float* Wp = W + (size_t)(bn + ar) * K + ac;
  float acc[8][8];
#pragma unroll
  for (int i = 0; i < 8; i++)
#pragma unroll
    for (int j = 0; j < 8; j++) acc[i][j] = 0.f;
  for (int k0 = 0; k0 < K; k0 += GBK) {
    float4 av = *(const float4*)(Ap + k0);
    float4 wv = *(const float4*)(Wp + k0);
    __syncthreads();
    As[ac + 0][ar] = av.x; As[ac + 1][ar] = av.y;
    As[ac + 2][ar] = av.z; As[ac + 3][ar] = av.w;
    Bs[ac + 0][ar] = wv.x; Bs[ac + 1][ar] = wv.y;
    Bs[ac + 2][ar] = wv.z; Bs[ac + 3][ar] = wv.w;
    __syncthreads();
#pragma unroll
    for (int kk = 0; kk < GBK; ++kk) {
      float a8[8], b8[8];
      *(float4*)&a8[0] = *(const float4*)&As[kk][ty * 8];
      *(float4*)&a8[4] = *(const float4*)&As[kk][ty * 8 + 4];
      *(float4*)&b8[0] = *(const float4*)&Bs[kk][tx * 8];
      *(float4*)&b8[4] = *(const float4*)&Bs[kk][tx * 8 + 4];
#pragma unroll
      for (int i = 0; i < 8; i++)
#pragma unroll
        for (int j = 0; j < 8; j++) acc[i][j] += a8[i] * b8[j];
    }
  }
  float bv[8];
#pragma unroll
  for (int j = 0; j < 8; j++) bv[j] = bias[bn + tx * 8 + j];
#pragma unroll
  for (int i = 0; i < 8; i++) {
    float* Crow = C + (size_t)(bm + ty * 8 + i) * N + bn + tx * 8;
#pragma unroll
    for (int j4 = 0; j4 < 2; j4++) {
      float4 o;
      o.x = acc[i][j4 * 4 + 0] + bv[j4 * 4 + 0];
      o.y = acc[i][j4 * 4 + 1] + bv[j4 * 4 + 1];
      o.z = acc[i][j4 * 4 + 2] + bv[j4 * 4 + 2];
      o.w = acc[i][j4 * 4 + 3] + bv[j4 * 4 + 3];
      if (relu) {
        o.x = fmaxf(o.x, 0.f); o.y = fmaxf(o.y, 0.f);
        o.z = fmaxf(o.z, 0.f); o.w = fmaxf(o.w, 0.f);
      }
      *(float4*)(Crow + j4 * 4) = o;
    }
  }
}

// ---------------- transpose K section: kT[b, c, t] = qkv[t*B+b, E + c] -------
__global__ __launch_bounds__(256) void transpose_k_kernel(
    const float* __restrict__ qkv, float* __restrict__ kT)
{
  __shared__ float tile[64][65];
  int c0 = blockIdx.x * 64;
  int t0 = blockIdx.y * 64;
  int b  = blockIdx.z;
  int tid = threadIdx.x;
  int cc = (tid & 15) * 4;
  int rr = tid >> 4;
#pragma unroll
  for (int it = 0; it < 4; ++it) {
    int row = rr + it * 16;
    float4 v = *(const float4*)&qkv[((size_t)(t0 + row) * BATCH + b) * E3 + EMB + c0 + cc];
    tile[row][cc + 0] = v.x; tile[row][cc + 1] = v.y;
    tile[row][cc + 2] = v.z; tile[row][cc + 3] = v.w;
  }
  __syncthreads();
  int t4 = (tid & 15) * 4;
#pragma unroll
  for (int it = 0; it < 4; ++it) {
    int ci = rr + it * 16;
    float4 v;
    v.x = tile[t4 + 0][ci]; v.y = tile[t4 + 1][ci];
    v.z = tile[t4 + 2][ci]; v.w = tile[t4 + 3][ci];
    *(float4*)&kT[((size_t)(b * EMB + c0 + ci)) * S_LEN + t0 + t4] = v;
  }
}

// ---------------- attention: block = (4 query rows, head, batch) -------------
__global__ __launch_bounds__(256) void attn_kernel(
    const float* __restrict__ qkv, const float* __restrict__ kT,
    const float* __restrict__ pos_sim, float* __restrict__ ctx)
{
  __shared__ float sc[4][S_LEN];        // 32 KB scores
  __shared__ float qld[4][DH];
  __shared__ float part[16][4][DH];     // 16 KB PV partials
  __shared__ float lrow[4];
  int tid = threadIdx.x;
  int s0 = blockIdx.x * 4;
  int h  = blockIdx.y;
  int b  = blockIdx.z;
  {
    int r = tid >> 6, d = tid & 63;
    qld[r][d] = qkv[((size_t)(s0 + r) * BATCH + b) * E3 + h * DH + d] * 0.125f;
  }
  __syncthreads();
  const float* kTh   = kT + ((size_t)(b * NH + h) * DH) * S_LEN;   // [d][t]
  const float* psrow = pos_sim + ((size_t)(b * S_LEN + s0)) * S_LEN;

  // ---- scores: each lane owns 4 consecutive t values per 1024-chunk ----
  for (int t0 = 0; t0 < S_LEN; t0 += 1024) {
    int t = t0 + tid * 4;
    float4 a0 = *(const float4*)&psrow[0 * S_LEN + t];
    float4 a1 = *(const float4*)&psrow[1 * S_LEN + t];
    float4 a2 = *(const float4*)&psrow[2 * S_LEN + t];
    float4 a3 = *(const float4*)&psrow[3 * S_LEN + t];
    for (int d = 0; d < DH; d += 4) {
      float4 q0 = *(const float4*)&qld[0][d];
      float4 q1 = *(const float4*)&qld[1][d];
      float4 q2 = *(const float4*)&qld[2][d];
      float4 q3 = *(const float4*)&qld[3][d];
#pragma unroll
      for (int u = 0; u < 4; ++u) {
        float4 kv = *(const float4*)&kTh[(size_t)(d + u) * S_LEN + t];
        float c0 = ((const float*)&q0)[u];
        float c1 = ((const float*)&q1)[u];
        float c2 = ((const float*)&q2)[u];
        float c3 = ((const float*)&q3)[u];
        a0.x += c0 * kv.x; a0.y += c0 * kv.y; a0.z += c0 * kv.z; a0.w += c0 * kv.w;
        a1.x += c1 * kv.x; a1.y += c1 * kv.y; a1.z += c1 * kv.z; a1.w += c1 * kv.w;
        a2.x += c2 * kv.x; a2.y += c2 * kv.y; a2.z += c2 * kv.z; a2.w += c2 * kv.w;
        a3.x += c3 * kv.x; a3.y += c3 * kv.y; a3.z += c3 * kv.z; a3.w += c3 * kv.w;
      }
    }
    *(float4*)&sc[0][t] = a0;
    *(float4*)&sc[1][t] = a1;
    *(float4*)&sc[2][t] = a2;
    *(float4*)&sc[3][t] = a3;
  }
  __syncthreads();

  // ---- softmax: wave r owns row r ----
  int r = tid >> 6, lane = tid & 63;
  float mx = -1e30f;
  for (int k = 0; k < S_LEN / 64; ++k) mx = fmaxf(mx, sc[r][lane + k * 64]);
#pragma unroll
  for (int off = 32; off >= 1; off >>= 1) mx = fmaxf(mx, __shfl_xor(mx, off, 64));
  float ls = 0.f;
  for (int k = 0; k < S_LEN / 64; ++k) {
    float p = __expf(sc[r][lane + k * 64] - mx);
    sc[r][lane + k * 64] = p;
    ls += p;
  }
#pragma unroll
  for (int off = 32; off >= 1; off >>= 1) ls += __shfl_xor(ls, off, 64);
  if (lane == 0) lrow[r] = ls;
  __syncthreads();

  // ---- PV: lane owns 4 d-cols (dd..dd+3), chunk c of 128 t values ----
  int c  = tid >> 4;
  int dd = (tid & 15) * 4;
  float o[4][4] = {{0.f}};
  const float* vbase = qkv + (size_t)b * E3 + 2 * EMB + h * DH + dd;
  for (int ti = 0; ti < 128; ti += 4) {
    int t = c * 128 + ti;
    float pr[4][4];
    *(float4*)pr[0] = *(const float4*)&sc[0][t];
    *(float4*)pr[1] = *(const float4*)&sc[1][t];
    *(float4*)pr[2] = *(const float4*)&sc[2][t];
    *(float4*)pr[3] = *(const float4*)&sc[3][t];
#pragma unroll
    for (int u = 0; u < 4; ++u) {
      float4 vv = *(const float4*)&vbase[(size_t)(t + u) * BATCH * E3];
#pragma unroll
      for (int rr = 0; rr < 4; ++rr) {
        o[rr][0] += pr[rr][u] * vv.x;
        o[rr][1] += pr[rr][u] * vv.y;
        o[rr][2] += pr[rr][u] * vv.z;
        o[rr][3] += pr[rr][u] * vv.w;
      }
    }
  }
#pragma unroll
  for (int rr = 0; rr < 4; ++rr)
    *(float4*)&part[c][rr][dd] = *(float4*)o[rr];
  __syncthreads();
  {
    float sum = 0.f;
    for (int cc = 0; cc < 16; ++cc) sum += part[cc][r][lane];
    float outv = sum / lrow[r];
    ctx[((size_t)(s0 + r) * BATCH + b) * EMB + h * DH + lane] = outv;
  }
}

// ---------------- layernorm(x1+x2)*g + b --------------------------------------
__global__ __launch_bounds__(256) void ln_kernel(
    const float* __restrict__ x1, const float* __restrict__ x2,
    const float* __restrict__ g, const float* __restrict__ bb,
    float* __restrict__ out)
{
  int row = blockIdx.x;
  int tid = threadIdx.x;
  const float* p1 = x1 + (size_t)row * EMB;
  const float* p2 = x2 + (size_t)row * EMB;
  float4 v1 = *(const float4*)&p1[tid * 4];
  float4 v2 = *(const float4*)&p2[tid * 4];
  float x[4] = {v1.x + v2.x, v1.y + v2.y, v1.z + v2.z, v1.w + v2.w};
  float s = x[0] + x[1] + x[2] + x[3];
  float s2 = x[0] * x[0] + x[1] * x[1] + x[2] * x[2] + x[3] * x[3];
#pragma unroll
  for (int off = 32; off >= 1; off >>= 1) {
    s  += __shfl_xor(s, off, 64);
    s2 += __shfl_xor(s2, off, 64);
  }
  __shared__ float ws1[4], ws2[4];
  int wid = tid >> 6, lane = tid & 63;
  if (lane == 0) { ws1[wid] = s; ws2[wid] = s2; }
  __syncthreads();
  s  = ws1[0] + ws1[1] + ws1[2] + ws1[3];
  s2 = ws2[0] + ws2[1] + ws2[2] + ws2[3];
  float mean = s * (1.f / EMB);
  float var  = s2 * (1.f / EMB) - mean * mean;
  float inv  = rsqrtf(var + 1e-5f);
  float4 gv = *(const float4*)&g[tid * 4];
  float4 bv = *(const float4*)&bb[tid * 4];
  float4 o;
  o.x = (x[0] - mean) * inv * gv.x + bv.x;
  o.y = (x[1] - mean) * inv * gv.y + bv.y;
  o.z = (x[2] - mean) * inv * gv.z + bv.z;
  o.w = (x[3] - mean) * inv * gv.w + bv.w;
  *(float4*)&out[(size_t)row * EMB + tid * 4] = o;
}

extern "C" void kernel_launch(void* const* d_in, const int* in_sizes, int n_in,
                              void* d_out, int out_size, void* d_ws, size_t ws_size,
                              hipStream_t stream)
{
  const float* src       = (const float*)d_in[0];
  const float* pos_embed = (const float*)d_in[1];
  const float* in_proj_w = (const float*)d_in[2];
  const float* in_proj_b = (const float*)d_in[3];
  const float* out_w     = (const float*)d_in[4];
  const float* out_b     = (const float*)d_in[5];
  const float* lin1_w    = (const float*)d_in[6];
  const float* lin1_b    = (const float*)d_in[7];
  const float* lin2_w    = (const float*)d_in[8];
  const float* lin2_b    = (const float*)d_in[9];
  const float* ln1_g     = (const float*)d_in[10];
  const float* ln1_b     = (const float*)d_in[11];
  const float* ln2_g     = (const float*)d_in[12];
  const float* ln2_b     = (const float*)d_in[13];
  const float* pos_w     = (const float*)d_in[14];
  const float* pos_b     = (const float*)d_in[15];
  float* out = (float*)d_out;
  float* ws  = (float*)d_ws;

  // workspace layout (floats). region0 = [pe | pos_sim | qkv], reused for
  // h1 (+proj tail) after attention is done. Total = 33,816,576 floats ≈ 135 MB.
  float* pe      = ws;                       // 262,144
  float* pos_sim = ws + 262144;              // 8,388,608
  float* qkv     = ws + 8650752;             // 12,582,912  (ends 21,233,664)
  float* h1      = ws;                       // 16,777,216  (reuse: after attn)
  float* proj    = ws + 16777216;            // 4,194,304   (inside region0 tail)
  float* kT      = ws + 21233664;            // 4,194,304
  float* ctxb    = ws + 25427968;            // 4,194,304
  float* xbuf    = ws + 29622272;            // 4,194,304   (ends 33,816,576)

  const int M = S_LEN * BATCH;  // 4096 rows, row index = s*B + b

  pe_kernel<<<dim3(S_LEN / 64, BATCH), 64, 0, stream>>>(pos_embed, pos_w, pos_b, pe);
  possim_kernel<<<dim3(S_LEN / 256, S_LEN, BATCH), 256, 0, stream>>>(pe, pos_sim);
  gemm_kernel<<<dim3(E3 / GBN, M / GBM), 256, 0, stream>>>(
      src, in_proj_w, in_proj_b, qkv, M, E3, EMB, 0);
  transpose_k_kernel<<<dim3(EMB / 64, S_LEN / 64, BATCH), 256, 0, stream>>>(qkv, kT);
  attn_kernel<<<dim3(S_LEN / 4, NH, BATCH), 256, 0, stream>>>(qkv, kT, pos_sim, ctxb);
  gemm_kernel<<<dim3(EMB / GBN, M / GBM), 256, 0, stream>>>(
      ctxb, out_w, out_b, proj, M, EMB, EMB, 0);
  ln_kernel<<<dim3(M), 256, 0, stream>>>(src, proj, ln1_g, ln1_b, xbuf);
  gemm_kernel<<<dim3(FF / GBN, M / GBM), 256, 0, stream>>>(
      xbuf, lin1_w, lin1_b, h1, M, FF, EMB, 1);
  gemm_kernel<<<dim3(EMB / GBN, M / GBM), 256, 0, stream>>>(
      h1, lin2_w, lin2_b, proj, M, EMB, FF, 0);
  ln_kernel<<<dim3(M), 256, 0, stream>>>(xbuf, proj, ln2_g, ln2_b, out);
}

// Round 2
// 1151.525 us; speedup vs baseline: 1.9962x; 1.9962x over previous
//
#include <hip/hip_runtime.h>
#include <hip/hip_bf16.h>
#include <math.h>

#define S_LEN 2048
#define BATCH 2
#define EMB   1024
#define NH    16
#define DH    64
#define E3    3072
#define FF    4096
#define PP    64

typedef __bf16 bf16x8 __attribute__((ext_vector_type(8)));
typedef float  floatx4 __attribute__((ext_vector_type(4)));

__device__ __forceinline__ void load_lds16(const void* g, void* l) {
  __builtin_amdgcn_global_load_lds(
      (const __attribute__((address_space(1))) void*)g,
      (__attribute__((address_space(3))) void*)l, 16, 0, 0);
}

// ---------------- fp32 -> bf16 convert (8 elems/thread) ----------------
__global__ __launch_bounds__(256) void cvt_kernel(
    const float* __restrict__ in, __hip_bfloat16* __restrict__ out, int n)
{
  int i = (blockIdx.x * 256 + threadIdx.x) * 8;
  if (i >= n) return;
  float4 a = *(const float4*)&in[i];
  float4 b = *(const float4*)&in[i + 4];
  __hip_bfloat16 t[8];
  t[0] = __float2bfloat16(a.x); t[1] = __float2bfloat16(a.y);
  t[2] = __float2bfloat16(a.z); t[3] = __float2bfloat16(a.w);
  t[4] = __float2bfloat16(b.x); t[5] = __float2bfloat16(b.y);
  t[6] = __float2bfloat16(b.z); t[7] = __float2bfloat16(b.w);
  *(float4*)&out[i] = *(float4*)t;
}

// ---------------- pos-embedding projection + L1 norm ----------------
__global__ __launch_bounds__(64) void pe_kernel(
    const float* __restrict__ pos_embed, const float* __restrict__ pos_w,
    const float* __restrict__ pos_b, float* __restrict__ pe)
{
  __shared__ float pw[PP * PP];
  int tid = threadIdx.x;
  for (int i = 0; i < PP; ++i) pw[i * PP + tid] = pos_w[i * PP + tid];
  __syncthreads();
  int s = blockIdx.x * 64 + tid;
  int b = blockIdx.y;
  float acc[PP];
#pragma unroll
  for (int q = 0; q < PP; ++q) acc[q] = pos_b[q];
  for (int p = 0; p < PP; ++p) {
    float x = pos_embed[(size_t)(b * PP + p) * S_LEN + s];
#pragma unroll
    for (int q = 0; q < PP; ++q) acc[q] += pw[q * PP + p] * x;
  }
  float l1 = 0.f;
#pragma unroll
  for (int q = 0; q < PP; ++q) l1 += fabsf(acc[q]);
  float inv = 1.f / fmaxf(l1, 1e-12f);
  for (int q = 0; q < PP; ++q)
    pe[(size_t)(b * PP + q) * S_LEN + s] = acc[q] * inv;
}

// ---------------- pos_sim[b,s,t] = sum_q pe[b,q,s]*pe[b,q,t] ----------------
__global__ __launch_bounds__(256) void possim_kernel(
    const float* __restrict__ pe, float* __restrict__ pos_sim)
{
  int t = blockIdx.x * 256 + threadIdx.x;
  int s = blockIdx.y;
  int b = blockIdx.z;
  const float* pb = pe + (size_t)b * PP * S_LEN;
  float a = 0.f;
#pragma unroll
  for (int q = 0; q < PP; ++q)
    a += pb[q * S_LEN + s] * pb[q * S_LEN + t];
  pos_sim[((size_t)(b * S_LEN + s)) * S_LEN + t] = a;
}

// ---------------- bf16 MFMA GEMM: C[M,N] = A[M,K] @ W[N,K]^T + bias ----------
// 128x128 tile, BK=64, 4 waves of 64x64 (4x4 16x16x32 frags), global_load_lds
// staging with XOR-swizzled colblocks so frag ds_read_b128 is conflict-free.
#define TM 128
#define TN 128
#define TK 64
__global__ __launch_bounds__(256) void gemm_bf16(
    const __hip_bfloat16* __restrict__ A, const __hip_bfloat16* __restrict__ W,
    const float* __restrict__ bias, float* __restrict__ Cf,
    __hip_bfloat16* __restrict__ Cb, int M, int N, int K, int relu)
{
  __shared__ __bf16 As[TM * TK];   // slot(row, cb) holds A[row][(cb^(row&7))*8 ..]
  __shared__ __bf16 Bs[TN * TK];
  int tid = threadIdx.x;
  int bm = blockIdx.y * TM;
  int bn = blockIdx.x * TN;
  int wave = tid >> 6, lane = tid & 63;
  int wm = (wave & 1) * 64, wn = (wave >> 1) * 64;

  int srow = tid >> 3;                 // 0..31 (row within 32-row chunk)
  int scb  = tid & 7;                  // LDS colblock slot 0..7
  int gcb  = scb ^ (srow & 7);         // global colblock (swizzle)
  const __hip_bfloat16* Ap = A + (size_t)(bm + srow) * K + gcb * 8;
  const __hip_bfloat16* Wp = W + (size_t)(bn + srow) * K + gcb * 8;
  __bf16* AsBase = As + tid * 8;
  __bf16* BsBase = Bs + tid * 8;

  int lrow = lane & 15;
  int lquad = lane >> 4;

  floatx4 acc[16];
#pragma unroll
  for (int i = 0; i < 16; ++i) acc[i] = (floatx4){0.f, 0.f, 0.f, 0.f};

  for (int k0 = 0; k0 < K; k0 += TK) {
    __syncthreads();
#pragma unroll
    for (int io = 0; io < 4; ++io) {
      load_lds16(Ap + (size_t)(32 * io) * K + k0, AsBase + io * 2048);
      load_lds16(Wp + (size_t)(32 * io) * K + k0, BsBase + io * 2048);
    }
    __syncthreads();
#pragma unroll
    for (int kc = 0; kc < 2; ++kc) {
      bf16x8 af[4], bfv[4];
      int kb = kc * 4 + lquad;
#pragma unroll
      for (int i = 0; i < 4; ++i) {
        int rowa = wm + i * 16 + lrow;
        af[i] = *(const bf16x8*)&As[rowa * 64 + (kb ^ (rowa & 7)) * 8];
        int rowb = wn + i * 16 + lrow;
        bfv[i] = *(const bf16x8*)&Bs[rowb * 64 + (kb ^ (rowb & 7)) * 8];
      }
#pragma unroll
      for (int i = 0; i < 4; ++i)
#pragma unroll
        for (int j = 0; j < 4; ++j)
          acc[i * 4 + j] = __builtin_amdgcn_mfma_f32_16x16x32_bf16(
              af[i], bfv[j], acc[i * 4 + j], 0, 0, 0);
    }
  }
  // epilogue: C/D layout col=lane&15, row=quad*4+reg
  int crow0 = bm + wm + lquad * 4;
  int ccol0 = bn + wn + lrow;
#pragma unroll
  for (int j = 0; j < 4; ++j) {
    int col = ccol0 + j * 16;
    float bv = bias[col];
#pragma unroll
    for (int i = 0; i < 4; ++i) {
#pragma unroll
      for (int r = 0; r < 4; ++r) {
        int row = crow0 + i * 16 + r;
        float v = acc[i * 4 + j][r] + bv;
        if (relu) v = fmaxf(v, 0.f);
        if (Cf) Cf[(size_t)row * N + col] = v;
        if (Cb) Cb[(size_t)row * N + col] = __float2bfloat16(v);
      }
    }
  }
}

// ---------------- transpose K section: kT[b, c, t] = qkv[t*B+b, E + c] -------
__global__ __launch_bounds__(256) void transpose_k_kernel(
    const float* __restrict__ qkv, float* __restrict__ kT)
{
  __shared__ float tile[64][65];
  int c0 = blockIdx.x * 64;
  int t0 = blockIdx.y * 64;
  int b  = blockIdx.z;
  int tid = threadIdx.x;
  int cc = (tid & 15) * 4;
  int rr = tid >> 4;
#pragma unroll
  for (int it = 0; it < 4; ++it) {
    int row = rr + it * 16;
    float4 v = *(const float4*)&qkv[((size_t)(t0 + row) * BATCH + b) * E3 + EMB + c0 + cc];
    tile[row][cc + 0] = v.x; tile[row][cc + 1] = v.y;
    tile[row][cc + 2] = v.z; tile[row][cc + 3] = v.w;
  }
  __syncthreads();
  int t4 = (tid & 15) * 4;
#pragma unroll
  for (int it = 0; it < 4; ++it) {
    int ci = rr + it * 16;
    float4 v;
    v.x = tile[t4 + 0][ci]; v.y = tile[t4 + 1][ci];
    v.z = tile[t4 + 2][ci]; v.w = tile[t4 + 3][ci];
    *(float4*)&kT[((size_t)(b * EMB + c0 + ci)) * S_LEN + t0 + t4] = v;
  }
}

// ---------------- attention: block = (4 query rows, head, batch) -------------
__global__ __launch_bounds__(256) void attn_kernel(
    const float* __restrict__ qkv, const float* __restrict__ kT,
    const float* __restrict__ pos_sim, __hip_bfloat16* __restrict__ ctx)
{
  __shared__ float sc[4][S_LEN];        // 32 KB scores
  __shared__ float qld[4][DH];
  __shared__ float part[16][4][DH];     // 16 KB PV partials
  __shared__ float lrow[4];
  int tid = threadIdx.x;
  int s0 = blockIdx.x * 4;
  int h  = blockIdx.y;
  int b  = blockIdx.z;
  {
    int r = tid >> 6, d = tid & 63;
    qld[r][d] = qkv[((size_t)(s0 + r) * BATCH + b) * E3 + h * DH + d] * 0.125f;
  }
  __syncthreads();
  const float* kTh   = kT + ((size_t)(b * NH + h) * DH) * S_LEN;   // [d][t]
  const float* psrow = pos_sim + ((size_t)(b * S_LEN + s0)) * S_LEN;

  for (int t0 = 0; t0 < S_LEN; t0 += 1024) {
    int t = t0 + tid * 4;
    float4 a0 = *(const float4*)&psrow[0 * S_LEN + t];
    float4 a1 = *(const float4*)&psrow[1 * S_LEN + t];
    float4 a2 = *(const float4*)&psrow[2 * S_LEN + t];
    float4 a3 = *(const float4*)&psrow[3 * S_LEN + t];
    for (int d = 0; d < DH; d += 4) {
      float4 q0 = *(const float4*)&qld[0][d];
      float4 q1 = *(const float4*)&qld[1][d];
      float4 q2 = *(const float4*)&qld[2][d];
      float4 q3 = *(const float4*)&qld[3][d];
#pragma unroll
      for (int u = 0; u < 4; ++u) {
        float4 kv = *(const float4*)&kTh[(size_t)(d + u) * S_LEN + t];
        float c0 = ((const float*)&q0)[u];
        float c1 = ((const float*)&q1)[u];
        float c2 = ((const float*)&q2)[u];
        float c3 = ((const float*)&q3)[u];
        a0.x += c0 * kv.x; a0.y += c0 * kv.y; a0.z += c0 * kv.z; a0.w += c0 * kv.w;
        a1.x += c1 * kv.x; a1.y += c1 * kv.y; a1.z += c1 * kv.z; a1.w += c1 * kv.w;
        a2.x += c2 * kv.x; a2.y += c2 * kv.y; a2.z += c2 * kv.z; a2.w += c2 * kv.w;
        a3.x += c3 * kv.x; a3.y += c3 * kv.y; a3.z += c3 * kv.z; a3.w += c3 * kv.w;
      }
    }
    *(float4*)&sc[0][t] = a0;
    *(float4*)&sc[1][t] = a1;
    *(float4*)&sc[2][t] = a2;
    *(float4*)&sc[3][t] = a3;
  }
  __syncthreads();

  int r = tid >> 6, lane = tid & 63;
  float mx = -1e30f;
  for (int k = 0; k < S_LEN / 64; ++k) mx = fmaxf(mx, sc[r][lane + k * 64]);
#pragma unroll
  for (int off = 32; off >= 1; off >>= 1) mx = fmaxf(mx, __shfl_xor(mx, off, 64));
  float ls = 0.f;
  for (int k = 0; k < S_LEN / 64; ++k) {
    float p = __expf(sc[r][lane + k * 64] - mx);
    sc[r][lane + k * 64] = p;
    ls += p;
  }
#pragma unroll
  for (int off = 32; off >= 1; off >>= 1) ls += __shfl_xor(ls, off, 64);
  if (lane == 0) lrow[r] = ls;
  __syncthreads();

  int c  = tid >> 4;
  int dd = (tid & 15) * 4;
  float o[4][4] = {{0.f}};
  const float* vbase = qkv + (size_t)b * E3 + 2 * EMB + h * DH + dd;
  for (int ti = 0; ti < 128; ti += 4) {
    int t = c * 128 + ti;
    float pr[4][4];
    *(float4*)pr[0] = *(const float4*)&sc[0][t];
    *(float4*)pr[1] = *(const float4*)&sc[1][t];
    *(float4*)pr[2] = *(const float4*)&sc[2][t];
    *(float4*)pr[3] = *(const float4*)&sc[3][t];
#pragma unroll
    for (int u = 0; u < 4; ++u) {
      float4 vv = *(const float4*)&vbase[(size_t)(t + u) * BATCH * E3];
#pragma unroll
      for (int rr = 0; rr < 4; ++rr) {
        o[rr][0] += pr[rr][u] * vv.x;
        o[rr][1] += pr[rr][u] * vv.y;
        o[rr][2] += pr[rr][u] * vv.z;
        o[rr][3] += pr[rr][u] * vv.w;
      }
    }
  }
#pragma unroll
  for (int rr = 0; rr < 4; ++rr)
    *(float4*)&part[c][rr][dd] = *(float4*)o[rr];
  __syncthreads();
  {
    float sum = 0.f;
    for (int cc = 0; cc < 16; ++cc) sum += part[cc][r][lane];
    float outv = sum / lrow[r];
    ctx[((size_t)(s0 + r) * BATCH + b) * EMB + h * DH + lane] = __float2bfloat16(outv);
  }
}

// ---------------- layernorm(x1+x2)*g + b, fp32 out + optional bf16 out -------
__global__ __launch_bounds__(256) void ln_kernel(
    const float* __restrict__ x1, const float* __restrict__ x2,
    const float* __restrict__ g, const float* __restrict__ bb,
    float* __restrict__ out, __hip_bfloat16* __restrict__ out_bf)
{
  int row = blockIdx.x;
  int tid = threadIdx.x;
  const float* p1 = x1 + (size_t)row * EMB;
  const float* p2 = x2 + (size_t)row * EMB;
  float4 v1 = *(const float4*)&p1[tid * 4];
  float4 v2 = *(const float4*)&p2[tid * 4];
  float x[4] = {v1.x + v2.x, v1.y + v2.y, v1.z + v2.z, v1.w + v2.w};
  float s = x[0] + x[1] + x[2] + x[3];
  float s2 = x[0] * x[0] + x[1] * x[1] + x[2] * x[2] + x[3] * x[3];
#pragma unroll
  for (int off = 32; off >= 1; off >>= 1) {
    s  += __shfl_xor(s, off, 64);
    s2 += __shfl_xor(s2, off, 64);
  }
  __shared__ float ws1[4], ws2[4];
  int wid = tid >> 6, lane = tid & 63;
  if (lane == 0) { ws1[wid] = s; ws2[wid] = s2; }
  __syncthreads();
  s  = ws1[0] + ws1[1] + ws1[2] + ws1[3];
  s2 = ws2[0] + ws2[1] + ws2[2] + ws2[3];
  float mean = s * (1.f / EMB);
  float var  = s2 * (1.f / EMB) - mean * mean;
  float inv  = rsqrtf(var + 1e-5f);
  float4 gv = *(const float4*)&g[tid * 4];
  float4 bv = *(const float4*)&bb[tid * 4];
  float4 o;
  o.x = (x[0] - mean) * inv * gv.x + bv.x;
  o.y = (x[1] - mean) * inv * gv.y + bv.y;
  o.z = (x[2] - mean) * inv * gv.z + bv.z;
  o.w = (x[3] - mean) * inv * gv.w + bv.w;
  *(float4*)&out[(size_t)row * EMB + tid * 4] = o;
  if (out_bf) {
    __hip_bfloat16 t[4];
    t[0] = __float2bfloat16(o.x); t[1] = __float2bfloat16(o.y);
    t[2] = __float2bfloat16(o.z); t[3] = __float2bfloat16(o.w);
    *(float2*)&out_bf[(size_t)row * EMB + tid * 4] = *(float2*)t;
  }
}

extern "C" void kernel_launch(void* const* d_in, const int* in_sizes, int n_in,
                              void* d_out, int out_size, void* d_ws, size_t ws_size,
                              hipStream_t stream)
{
  const float* src       = (const float*)d_in[0];
  const float* pos_embed = (const float*)d_in[1];
  const float* in_proj_w = (const float*)d_in[2];
  const float* in_proj_b = (const float*)d_in[3];
  const float* out_w     = (const float*)d_in[4];
  const float* out_b     = (const float*)d_in[5];
  const float* lin1_w    = (const float*)d_in[6];
  const float* lin1_b    = (const float*)d_in[7];
  const float* lin2_w    = (const float*)d_in[8];
  const float* lin2_b    = (const float*)d_in[9];
  const float* ln1_g     = (const float*)d_in[10];
  const float* ln1_b     = (const float*)d_in[11];
  const float* ln2_g     = (const float*)d_in[12];
  const float* ln2_b     = (const float*)d_in[13];
  const float* pos_w     = (const float*)d_in[14];
  const float* pos_b     = (const float*)d_in[15];
  float* out = (float*)d_out;
  float* ws  = (float*)d_ws;

  // ---- workspace layout (float units), peak 33,816,576 floats ≈ 135 MB ----
  // Phase 1 (through attn):
  float* pe      = ws;                       // 262,144
  float* pos_sim = ws + 262144;              // 8,388,608 (ends 8,650,752)
  float* qkv     = ws + 8650752;             // 12,582,912 (ends 21,233,664)
  float* kT      = ws + 21233664;            // 4,194,304 (ends 25,427,968)
  __hip_bfloat16* src_bf = (__hip_bfloat16*)(ws + 25427968);  // 4,194,304 elems (2,097,152 fl)
  float* xbuf    = ws + 29622272;            // 4,194,304 (ends 33,816,576)
  // weight bf16 staging in xbuf slot (dead once ln1 writes xbuf):
  __hip_bfloat16* inw_bf  = (__hip_bfloat16*)(ws + 29622272); // 3,145,728 elems
  __hip_bfloat16* outw_bf = (__hip_bfloat16*)(ws + 31195136); // 1,048,576 elems
  // Phase 2 (after attn; region A reuse):
  __hip_bfloat16* ctx_bf = (__hip_bfloat16*)(ws + 25427968);  // src_bf slot, 4,194,304 elems
  __hip_bfloat16* x_bf   = (__hip_bfloat16*)ws;               // 4,194,304 elems (2,097,152 fl)
  __hip_bfloat16* h1_bf  = (__hip_bfloat16*)(ws + 2097152);   // 16,777,216 elems (8,388,608 fl)
  float* proj            = ws + 10485760;    // 4,194,304 (ends 14,680,064)
  float* proj2           = ws + 14680064;    // 4,194,304 (ends 18,874,368)
  __hip_bfloat16* l1w_bf = (__hip_bfloat16*)(ws + 21233664);  // kT slot, 4,194,304 elems
  __hip_bfloat16* l2w_bf = (__hip_bfloat16*)(ws + 23330816);  // 4,194,304 elems

  const int M = S_LEN * BATCH;  // 4096 rows, row index = s*B + b

  cvt_kernel<<<4194304 / 2048, 256, 0, stream>>>(src, src_bf, 4194304);
  cvt_kernel<<<3145728 / 2048, 256, 0, stream>>>(in_proj_w, inw_bf, 3145728);
  cvt_kernel<<<1048576 / 2048, 256, 0, stream>>>(out_w, outw_bf, 1048576);
  pe_kernel<<<dim3(S_LEN / 64, BATCH), 64, 0, stream>>>(pos_embed, pos_w, pos_b, pe);
  possim_kernel<<<dim3(S_LEN / 256, S_LEN, BATCH), 256, 0, stream>>>(pe, pos_sim);
  gemm_bf16<<<dim3(E3 / TN, M / TM), 256, 0, stream>>>(
      src_bf, inw_bf, in_proj_b, qkv, nullptr, M, E3, EMB, 0);
  transpose_k_kernel<<<dim3(EMB / 64, S_LEN / 64, BATCH), 256, 0, stream>>>(qkv, kT);
  attn_kernel<<<dim3(S_LEN / 4, NH, BATCH), 256, 0, stream>>>(qkv, kT, pos_sim, ctx_bf);
  cvt_kernel<<<4194304 / 2048, 256, 0, stream>>>(lin1_w, l1w_bf, 4194304);
  cvt_kernel<<<4194304 / 2048, 256, 0, stream>>>(lin2_w, l2w_bf, 4194304);
  gemm_bf16<<<dim3(EMB / TN, M / TM), 256, 0, stream>>>(
      ctx_bf, outw_bf, out_b, proj, nullptr, M, EMB, EMB, 0);
  ln_kernel<<<dim3(M), 256, 0, stream>>>(src, proj, ln1_g, ln1_b, xbuf, x_bf);
  gemm_bf16<<<dim3(FF / TN, M / TM), 256, 0, stream>>>(
      x_bf, l1w_bf, lin1_b, nullptr, h1_bf, M, FF, EMB, 1);
  gemm_bf16<<<dim3(EMB / TN, M / TM), 256, 0, stream>>>(
      h1_bf, l2w_bf, lin2_b, proj2, nullptr, M, EMB, FF, 0);
  ln_kernel<<<dim3(M), 256, 0, stream>>>(xbuf, proj2, ln2_g, ln2_b, out, nullptr);
}

// Round 3
// 588.915 us; speedup vs baseline: 3.9032x; 1.9553x over previous
//
#include <hip/hip_runtime.h>
#include <hip/hip_bf16.h>
#include <math.h>

#define S_LEN 2048
#define BATCH 2
#define EMB   1024
#define NH    16
#define DH    64
#define E3    3072
#define FF    4096
#define PP    64

typedef __bf16 bf16x8 __attribute__((ext_vector_type(8)));
typedef float  floatx4 __attribute__((ext_vector_type(4)));

__device__ __forceinline__ void load_lds16(const void* g, void* l) {
  __builtin_amdgcn_global_load_lds(
      (const __attribute__((address_space(1))) void*)g,
      (__attribute__((address_space(3))) void*)l, 16, 0, 0);
}

// ---------------- fp32 -> bf16 convert (8 elems/thread) ----------------
__global__ __launch_bounds__(256) void cvt_kernel(
    const float* __restrict__ in, __hip_bfloat16* __restrict__ out, int n)
{
  int i = (blockIdx.x * 256 + threadIdx.x) * 8;
  if (i >= n) return;
  float4 a = *(const float4*)&in[i];
  float4 b = *(const float4*)&in[i + 4];
  __hip_bfloat16 t[8];
  t[0] = __float2bfloat16(a.x); t[1] = __float2bfloat16(a.y);
  t[2] = __float2bfloat16(a.z); t[3] = __float2bfloat16(a.w);
  t[4] = __float2bfloat16(b.x); t[5] = __float2bfloat16(b.y);
  t[6] = __float2bfloat16(b.z); t[7] = __float2bfloat16(b.w);
  *(float4*)&out[i] = *(float4*)t;
}

// ---------------- pos-embedding projection + L1 norm ----------------
__global__ __launch_bounds__(64) void pe_kernel(
    const float* __restrict__ pos_embed, const float* __restrict__ pos_w,
    const float* __restrict__ pos_b, float* __restrict__ pe)
{
  __shared__ float pw[PP * PP];
  int tid = threadIdx.x;
  for (int i = 0; i < PP; ++i) pw[i * PP + tid] = pos_w[i * PP + tid];
  __syncthreads();
  int s = blockIdx.x * 64 + tid;
  int b = blockIdx.y;
  float acc[PP];
#pragma unroll
  for (int q = 0; q < PP; ++q) acc[q] = pos_b[q];
  for (int p = 0; p < PP; ++p) {
    float x = pos_embed[(size_t)(b * PP + p) * S_LEN + s];
#pragma unroll
    for (int q = 0; q < PP; ++q) acc[q] += pw[q * PP + p] * x;
  }
  float l1 = 0.f;
#pragma unroll
  for (int q = 0; q < PP; ++q) l1 += fabsf(acc[q]);
  float inv = 1.f / fmaxf(l1, 1e-12f);
  for (int q = 0; q < PP; ++q)
    pe[(size_t)(b * PP + q) * S_LEN + s] = acc[q] * inv;
}

// ---------------- pos_sim[b,s,t] = sum_q pe[b,q,s]*pe[b,q,t] ----------------
__global__ __launch_bounds__(256) void possim_kernel(
    const float* __restrict__ pe, float* __restrict__ pos_sim)
{
  int t = blockIdx.x * 256 + threadIdx.x;
  int s = blockIdx.y;
  int b = blockIdx.z;
  const float* pb = pe + (size_t)b * PP * S_LEN;
  float a = 0.f;
#pragma unroll
  for (int q = 0; q < PP; ++q)
    a += pb[q * S_LEN + s] * pb[q * S_LEN + t];
  pos_sim[((size_t)(b * S_LEN + s)) * S_LEN + t] = a;
}

// ---------------- bf16 MFMA GEMM: C[M,N] = A[M,K] @ W[N,K]^T + bias ----------
#define TM 128
#define TN 128
#define TK 64
__global__ __launch_bounds__(256) void gemm_bf16(
    const __hip_bfloat16* __restrict__ A, const __hip_bfloat16* __restrict__ W,
    const float* __restrict__ bias, float* __restrict__ Cf,
    __hip_bfloat16* __restrict__ Cb, int M, int N, int K, int relu)
{
  __shared__ __bf16 As[TM * TK];
  __shared__ __bf16 Bs[TN * TK];
  int tid = threadIdx.x;
  int bm = blockIdx.y * TM;
  int bn = blockIdx.x * TN;
  int wave = tid >> 6, lane = tid & 63;
  int wm = (wave & 1) * 64, wn = (wave >> 1) * 64;

  int srow = tid >> 3;
  int scb  = tid & 7;
  int gcb  = scb ^ (srow & 7);
  const __hip_bfloat16* Ap = A + (size_t)(bm + srow) * K + gcb * 8;
  const __hip_bfloat16* Wp = W + (size_t)(bn + srow) * K + gcb * 8;
  __bf16* AsBase = As + tid * 8;
  __bf16* BsBase = Bs + tid * 8;

  int lrow = lane & 15;
  int lquad = lane >> 4;

  floatx4 acc[16];
#pragma unroll
  for (int i = 0; i < 16; ++i) acc[i] = (floatx4){0.f, 0.f, 0.f, 0.f};

  for (int k0 = 0; k0 < K; k0 += TK) {
    __syncthreads();
#pragma unroll
    for (int io = 0; io < 4; ++io) {
      load_lds16(Ap + (size_t)(32 * io) * K + k0, AsBase + io * 2048);
      load_lds16(Wp + (size_t)(32 * io) * K + k0, BsBase + io * 2048);
    }
    __syncthreads();
#pragma unroll
    for (int kc = 0; kc < 2; ++kc) {
      bf16x8 af[4], bfv[4];
      int kb = kc * 4 + lquad;
#pragma unroll
      for (int i = 0; i < 4; ++i) {
        int rowa = wm + i * 16 + lrow;
        af[i] = *(const bf16x8*)&As[rowa * 64 + (kb ^ (rowa & 7)) * 8];
        int rowb = wn + i * 16 + lrow;
        bfv[i] = *(const bf16x8*)&Bs[rowb * 64 + (kb ^ (rowb & 7)) * 8];
      }
#pragma unroll
      for (int i = 0; i < 4; ++i)
#pragma unroll
        for (int j = 0; j < 4; ++j)
          acc[i * 4 + j] = __builtin_amdgcn_mfma_f32_16x16x32_bf16(
              af[i], bfv[j], acc[i * 4 + j], 0, 0, 0);
    }
  }
  int crow0 = bm + wm + lquad * 4;
  int ccol0 = bn + wn + lrow;
#pragma unroll
  for (int j = 0; j < 4; ++j) {
    int col = ccol0 + j * 16;
    float bv = bias[col];
#pragma unroll
    for (int i = 0; i < 4; ++i) {
#pragma unroll
      for (int r = 0; r < 4; ++r) {
        int row = crow0 + i * 16 + r;
        float v = acc[i * 4 + j][r] + bv;
        if (relu) v = fmaxf(v, 0.f);
        if (Cf) Cf[(size_t)row * N + col] = v;
        if (Cb) Cb[(size_t)row * N + col] = __float2bfloat16(v);
      }
    }
  }
}

// ---------------- transpose V: vT[b, c, t] = qkv_bf[t*B+b, 2E + c] ----------
__global__ __launch_bounds__(256) void transpose_v(
    const __hip_bfloat16* __restrict__ qkv, __hip_bfloat16* __restrict__ vT)
{
  __shared__ __hip_bfloat16 tile[64][72];
  int c0 = blockIdx.x * 64, t0 = blockIdx.y * 64, b = blockIdx.z;
  int tid = threadIdx.x;
#pragma unroll
  for (int i = 0; i < 2; ++i) {
    int k = tid * 2 + i;
    int row = k >> 3, col = (k & 7) * 8;
    float4 v = *(const float4*)&qkv[((size_t)(t0 + row) * BATCH + b) * E3 + 2 * EMB + c0 + col];
    __hip_bfloat16 tmp[8];
    *(float4*)tmp = v;
#pragma unroll
    for (int j = 0; j < 8; ++j) tile[row][col + j] = tmp[j];
  }
  __syncthreads();
#pragma unroll
  for (int i = 0; i < 2; ++i) {
    int k = tid * 2 + i;
    int crow = k >> 3, tcol = (k & 7) * 8;
    __hip_bfloat16 tmp[8];
#pragma unroll
    for (int j = 0; j < 8; ++j) tmp[j] = tile[tcol + j][crow];
    *(float4*)&vT[((size_t)(b * EMB + c0 + crow)) * S_LEN + t0 + tcol] = *(float4*)tmp;
  }
}

// ---------------- MFMA flash attention ---------------------------------------
// block = 64 q-rows x (head h, batch b); 4 waves x 16 q-rows; K-tiles of 64.
__global__ __launch_bounds__(256) void attn_mfma(
    const __hip_bfloat16* __restrict__ qkv,   // [S*B][E3] bf16
    const __hip_bfloat16* __restrict__ vT,    // [B][EMB][S] bf16
    const float* __restrict__ pos_sim,        // [B][S][S] fp32
    __hip_bfloat16* __restrict__ ctx)         // [S*B][EMB] bf16
{
  __shared__ __bf16 Qs[4096];      // [64 q][64 d], colblock-swizzled
  __shared__ __bf16 Ks[4096];      // [64 k][64 d], swizzled
  __shared__ __bf16 Vs[4096];      // [64 d][64 k] (V^T), swizzled
  __shared__ __bf16 Ps[4][1024];   // per-wave [16 q][64 k], swizzled
  int tid = threadIdx.x;
  int q0 = blockIdx.x * 64;
  int h  = blockIdx.y;
  int b  = blockIdx.z;
  int w = tid >> 6, lane = tid & 63;
  int quad = lane >> 4, r15 = lane & 15;

  int srow = tid >> 3;          // staging row 0..31 (per 32-row chunk)
  int scb  = tid & 7;           // LDS colblock slot
  // ---- stage Q (once) and first K/V tile ----
  {
    const __hip_bfloat16* qbase = qkv + (size_t)h * DH;
#pragma unroll
    for (int i = 0; i < 2; ++i) {
      int row = i * 32 + srow;
      int gcb = scb ^ (row & 7);
      load_lds16(qbase + ((size_t)(q0 + row) * BATCH + b) * E3 + gcb * 8,
                 Qs + i * 2048 + tid * 8);
    }
    const __hip_bfloat16* kbase = qkv + EMB + (size_t)h * DH;
    const __hip_bfloat16* vbase = vT + ((size_t)b * EMB + h * DH) * S_LEN;
#pragma unroll
    for (int i = 0; i < 2; ++i) {
      int row = i * 32 + srow;
      int gcb = scb ^ (row & 7);
      load_lds16(kbase + ((size_t)row * BATCH + b) * E3 + gcb * 8,
                 Ks + i * 2048 + tid * 8);
      load_lds16(vbase + (size_t)row * S_LEN + gcb * 8,
                 Vs + i * 2048 + tid * 8);
    }
  }
  __syncthreads();

  bf16x8 qa[2];
  {
    int row = w * 16 + r15;
#pragma unroll
    for (int kc = 0; kc < 2; ++kc)
      qa[kc] = *(const bf16x8*)&Qs[row * 64 + ((kc * 4 + quad) ^ (r15 & 7)) * 8];
  }

  floatx4 of[4];
#pragma unroll
  for (int j = 0; j < 4; ++j) of[j] = (floatx4){0.f, 0.f, 0.f, 0.f};
  float m_run[4], l_run[4];
#pragma unroll
  for (int r = 0; r < 4; ++r) { m_run[r] = -1e30f; l_run[r] = 0.f; }

  const float* psbase =
      pos_sim + ((size_t)(b * S_LEN + q0 + w * 16 + quad * 4)) * S_LEN + r15;
  __bf16* pw = &Ps[w][0];

  for (int kt = 0; kt < 32; ++kt) {
    int t0 = kt * 64;
    // pos_sim tile (fp32, L3-resident)
    float ps[4][4];
#pragma unroll
    for (int j = 0; j < 4; ++j)
#pragma unroll
      for (int r = 0; r < 4; ++r)
        ps[j][r] = psbase[(size_t)r * S_LEN + t0 + j * 16];

    // ---- S = Q K^T * 0.125 + ps ----
    floatx4 sf[4];
#pragma unroll
    for (int j = 0; j < 4; ++j) {
      int rowk = j * 16 + r15;
      bf16x8 kb0 = *(const bf16x8*)&Ks[rowk * 64 + ((quad) ^ (r15 & 7)) * 8];
      bf16x8 kb1 = *(const bf16x8*)&Ks[rowk * 64 + ((4 + quad) ^ (r15 & 7)) * 8];
      sf[j] = __builtin_amdgcn_mfma_f32_16x16x32_bf16(
          qa[0], kb0, (floatx4){0.f, 0.f, 0.f, 0.f}, 0, 0, 0);
      sf[j] = __builtin_amdgcn_mfma_f32_16x16x32_bf16(qa[1], kb1, sf[j], 0, 0, 0);
    }
#pragma unroll
    for (int j = 0; j < 4; ++j)
#pragma unroll
      for (int r = 0; r < 4; ++r)
        sf[j][r] = sf[j][r] * 0.125f + ps[j][r];

    // ---- online softmax (rows = quad*4+r, reduce over 16 lanes) ----
    float mnew[4], alpha[4];
#pragma unroll
    for (int r = 0; r < 4; ++r) {
      float v = fmaxf(fmaxf(sf[0][r], sf[1][r]), fmaxf(sf[2][r], sf[3][r]));
#pragma unroll
      for (int mask = 1; mask <= 8; mask <<= 1)
        v = fmaxf(v, __shfl_xor(v, mask, 64));
      mnew[r] = fmaxf(m_run[r], v);
      alpha[r] = __expf(m_run[r] - mnew[r]);
      m_run[r] = mnew[r];
    }
#pragma unroll
    for (int j = 0; j < 4; ++j)
#pragma unroll
      for (int r = 0; r < 4; ++r)
        sf[j][r] = __expf(sf[j][r] - mnew[r]);
    float rs[4];
#pragma unroll
    for (int r = 0; r < 4; ++r) {
      float v = sf[0][r] + sf[1][r] + sf[2][r] + sf[3][r];
#pragma unroll
      for (int mask = 1; mask <= 8; mask <<= 1)
        v += __shfl_xor(v, mask, 64);
      rs[r] = v;
      l_run[r] = l_run[r] * alpha[r] + rs[r];
    }
    // rescale O
#pragma unroll
    for (int jd = 0; jd < 4; ++jd)
#pragma unroll
      for (int r = 0; r < 4; ++r)
        of[jd][r] *= alpha[r];

    // ---- write P (bf16) to per-wave LDS, C-layout -> A-layout ----
#pragma unroll
    for (int j = 0; j < 4; ++j) {
      int cb = j * 2 + (r15 >> 3);
#pragma unroll
      for (int r = 0; r < 4; ++r) {
        int row = quad * 4 + r;
        pw[row * 64 + ((cb ^ (row & 7)) * 8) + (r15 & 7)] = (__bf16)sf[j][r];
      }
    }
    __asm__ volatile("s_waitcnt lgkmcnt(0)" ::: "memory");
    bf16x8 pa0 = *(const bf16x8*)&pw[r15 * 64 + ((quad) ^ (r15 & 7)) * 8];
    bf16x8 pa1 = *(const bf16x8*)&pw[r15 * 64 + ((4 + quad) ^ (r15 & 7)) * 8];

    // ---- O += P V ----
#pragma unroll
    for (int jd = 0; jd < 4; ++jd) {
      int rowd = jd * 16 + r15;
      bf16x8 vb0 = *(const bf16x8*)&Vs[rowd * 64 + ((quad) ^ (r15 & 7)) * 8];
      bf16x8 vb1 = *(const bf16x8*)&Vs[rowd * 64 + ((4 + quad) ^ (r15 & 7)) * 8];
      of[jd] = __builtin_amdgcn_mfma_f32_16x16x32_bf16(pa0, vb0, of[jd], 0, 0, 0);
      of[jd] = __builtin_amdgcn_mfma_f32_16x16x32_bf16(pa1, vb1, of[jd], 0, 0, 0);
    }

    // ---- stage next K/V tile ----
    if (kt < 31) {
      __syncthreads();
      int tn = t0 + 64;
      const __hip_bfloat16* kbase = qkv + EMB + (size_t)h * DH;
      const __hip_bfloat16* vbase = vT + ((size_t)b * EMB + h * DH) * S_LEN + tn;
#pragma unroll
      for (int i = 0; i < 2; ++i) {
        int row = i * 32 + srow;
        int gcb = scb ^ (row & 7);
        load_lds16(kbase + ((size_t)(tn + row) * BATCH + b) * E3 + gcb * 8,
                   Ks + i * 2048 + tid * 8);
        load_lds16(vbase + (size_t)row * S_LEN + gcb * 8,
                   Vs + i * 2048 + tid * 8);
      }
      __syncthreads();
    }
  }

  // ---- epilogue: O / l ----
#pragma unroll
  for (int r = 0; r < 4; ++r) {
    float inv = 1.f / l_run[r];
    int qrow = q0 + w * 16 + quad * 4 + r;
    __hip_bfloat16* crow = ctx + ((size_t)qrow * BATCH + b) * EMB + h * DH + r15;
#pragma unroll
    for (int jd = 0; jd < 4; ++jd)
      crow[jd * 16] = __float2bfloat16(of[jd][r] * inv);
  }
}

// ---------------- layernorm(x1+x2)*g + b, fp32 out + optional bf16 out -------
__global__ __launch_bounds__(256) void ln_kernel(
    const float* __restrict__ x1, const float* __restrict__ x2,
    const float* __restrict__ g, const float* __restrict__ bb,
    float* __restrict__ out, __hip_bfloat16* __restrict__ out_bf)
{
  int row = blockIdx.x;
  int tid = threadIdx.x;
  const float* p1 = x1 + (size_t)row * EMB;
  const float* p2 = x2 + (size_t)row * EMB;
  float4 v1 = *(const float4*)&p1[tid * 4];
  float4 v2 = *(const float4*)&p2[tid * 4];
  float x[4] = {v1.x + v2.x, v1.y + v2.y, v1.z + v2.z, v1.w + v2.w};
  float s = x[0] + x[1] + x[2] + x[3];
  float s2 = x[0] * x[0] + x[1] * x[1] + x[2] * x[2] + x[3] * x[3];
#pragma unroll
  for (int off = 32; off >= 1; off >>= 1) {
    s  += __shfl_xor(s, off, 64);
    s2 += __shfl_xor(s2, off, 64);
  }
  __shared__ float ws1[4], ws2[4];
  int wid = tid >> 6, lane = tid & 63;
  if (lane == 0) { ws1[wid] = s; ws2[wid] = s2; }
  __syncthreads();
  s  = ws1[0] + ws1[1] + ws1[2] + ws1[3];
  s2 = ws2[0] + ws2[1] + ws2[2] + ws2[3];
  float mean = s * (1.f / EMB);
  float var  = s2 * (1.f / EMB) - mean * mean;
  float inv  = rsqrtf(var + 1e-5f);
  float4 gv = *(const float4*)&g[tid * 4];
  float4 bv = *(const float4*)&bb[tid * 4];
  float4 o;
  o.x = (x[0] - mean) * inv * gv.x + bv.x;
  o.y = (x[1] - mean) * inv * gv.y + bv.y;
  o.z = (x[2] - mean) * inv * gv.z + bv.z;
  o.w = (x[3] - mean) * inv * gv.w + bv.w;
  *(float4*)&out[(size_t)row * EMB + tid * 4] = o;
  if (out_bf) {
    __hip_bfloat16 t[4];
    t[0] = __float2bfloat16(o.x); t[1] = __float2bfloat16(o.y);
    t[2] = __float2bfloat16(o.z); t[3] = __float2bfloat16(o.w);
    *(float2*)&out_bf[(size_t)row * EMB + tid * 4] = *(float2*)t;
  }
}

extern "C" void kernel_launch(void* const* d_in, const int* in_sizes, int n_in,
                              void* d_out, int out_size, void* d_ws, size_t ws_size,
                              hipStream_t stream)
{
  const float* src       = (const float*)d_in[0];
  const float* pos_embed = (const float*)d_in[1];
  const float* in_proj_w = (const float*)d_in[2];
  const float* in_proj_b = (const float*)d_in[3];
  const float* out_w     = (const float*)d_in[4];
  const float* out_b     = (const float*)d_in[5];
  const float* lin1_w    = (const float*)d_in[6];
  const float* lin1_b    = (const float*)d_in[7];
  const float* lin2_w    = (const float*)d_in[8];
  const float* lin2_b    = (const float*)d_in[9];
  const float* ln1_g     = (const float*)d_in[10];
  const float* ln1_b     = (const float*)d_in[11];
  const float* ln2_g     = (const float*)d_in[12];
  const float* ln2_b     = (const float*)d_in[13];
  const float* pos_w     = (const float*)d_in[14];
  const float* pos_b     = (const float*)d_in[15];
  float* out = (float*)d_out;
  float* ws  = (float*)d_ws;

  // ---- workspace layout (float units), peak 31,719,424 floats ≈ 127 MB ----
  float* pe      = ws;                                         // 262,144
  float* pos_sim = ws + 262144;                                // 8,388,608 -> 8,650,752
  __hip_bfloat16* qkv_bf = (__hip_bfloat16*)(ws + 8650752);    // 12,582,912 el -> 14,942,208 fl
  __hip_bfloat16* vT_bf  = (__hip_bfloat16*)(ws + 14942208);   // 4,194,304 el -> 17,039,360
  __hip_bfloat16* src_bf = (__hip_bfloat16*)(ws + 17039360);   // 4,194,304 el -> 19,136,512
  __hip_bfloat16* inw_bf  = (__hip_bfloat16*)(ws + 19136512);  // 3,145,728 el -> 20,709,376
  __hip_bfloat16* outw_bf = (__hip_bfloat16*)(ws + 20709376);  // 1,048,576 el -> 21,233,664
  __hip_bfloat16* ctx_bf = (__hip_bfloat16*)(ws + 21233664);   // 4,194,304 el -> 23,330,816
  __hip_bfloat16* l1w_bf = (__hip_bfloat16*)(ws + 23330816);   // 4,194,304 el -> 25,427,968
  __hip_bfloat16* l2w_bf = (__hip_bfloat16*)(ws + 25427968);   // 4,194,304 el -> 27,525,120
  float* proj            = ws + 27525120;                      // 4,194,304 -> 31,719,424
  // phase-2 reuse (pe/pos_sim/qkv/vT dead after attn):
  __hip_bfloat16* x_bf   = (__hip_bfloat16*)ws;                // 4,194,304 el (0..2,097,152 fl)
  float* xbuf            = ws + 2097152;                       // 4,194,304 -> 6,291,456
  __hip_bfloat16* h1_bf  = (__hip_bfloat16*)(ws + 6291456);    // 16,777,216 el -> 14,680,064 fl

  const int M = S_LEN * BATCH;  // 4096 rows, row = s*B + b

  cvt_kernel<<<4194304 / 2048, 256, 0, stream>>>(src, src_bf, 4194304);
  cvt_kernel<<<3145728 / 2048, 256, 0, stream>>>(in_proj_w, inw_bf, 3145728);
  cvt_kernel<<<1048576 / 2048, 256, 0, stream>>>(out_w, outw_bf, 1048576);
  cvt_kernel<<<4194304 / 2048, 256, 0, stream>>>(lin1_w, l1w_bf, 4194304);
  cvt_kernel<<<4194304 / 2048, 256, 0, stream>>>(lin2_w, l2w_bf, 4194304);
  pe_kernel<<<dim3(S_LEN / 64, BATCH), 64, 0, stream>>>(pos_embed, pos_w, pos_b, pe);
  possim_kernel<<<dim3(S_LEN / 256, S_LEN, BATCH), 256, 0, stream>>>(pe, pos_sim);
  gemm_bf16<<<dim3(E3 / TN, M / TM), 256, 0, stream>>>(
      src_bf, inw_bf, in_proj_b, nullptr, qkv_bf, M, E3, EMB, 0);
  transpose_v<<<dim3(EMB / 64, S_LEN / 64, BATCH), 256, 0, stream>>>(qkv_bf, vT_bf);
  attn_mfma<<<dim3(S_LEN / 64, NH, BATCH), 256, 0, stream>>>(
      qkv_bf, vT_bf, pos_sim, ctx_bf);
  gemm_bf16<<<dim3(EMB / TN, M / TM), 256, 0, stream>>>(
      ctx_bf, outw_bf, out_b, proj, nullptr, M, EMB, EMB, 0);
  ln_kernel<<<dim3(M), 256, 0, stream>>>(src, proj, ln1_g, ln1_b, xbuf, x_bf);
  gemm_bf16<<<dim3(FF / TN, M / TM), 256, 0, stream>>>(
      x_bf, l1w_bf, lin1_b, nullptr, h1_bf, M, FF, EMB, 1);
  gemm_bf16<<<dim3(EMB / TN, M / TM), 256, 0, stream>>>(
      h1_bf, l2w_bf, lin2_b, proj, nullptr, M, EMB, FF, 0);
  ln_kernel<<<dim3(M), 256, 0, stream>>>(xbuf, proj, ln2_g, ln2_b, out, nullptr);
}

// Round 5
// 515.065 us; speedup vs baseline: 4.4628x; 1.1434x over previous
//
#include <hip/hip_runtime.h>
#include <hip/hip_bf16.h>
#include <math.h>

#define S_LEN 2048
#define BATCH 2
#define EMB   1024
#define NH    16
#define DH    64
#define E3    3072
#define FF    4096
#define PP    64

typedef __bf16 bf16x8 __attribute__((ext_vector_type(8)));
typedef float  floatx4 __attribute__((ext_vector_type(4)));

__device__ __forceinline__ void load_lds16(const void* g, void* l) {
  __builtin_amdgcn_global_load_lds(
      (const __attribute__((address_space(1))) void*)g,
      (__attribute__((address_space(3))) void*)l, 16, 0, 0);
}

// ---------------- fp32 -> bf16 convert (8 elems/thread) ----------------
__global__ __launch_bounds__(256) void cvt_kernel(
    const float* __restrict__ in, __hip_bfloat16* __restrict__ out, int n)
{
  int i = (blockIdx.x * 256 + threadIdx.x) * 8;
  if (i >= n) return;
  float4 a = *(const float4*)&in[i];
  float4 b = *(const float4*)&in[i + 4];
  __hip_bfloat16 t[8];
  t[0] = __float2bfloat16(a.x); t[1] = __float2bfloat16(a.y);
  t[2] = __float2bfloat16(a.z); t[3] = __float2bfloat16(a.w);
  t[4] = __float2bfloat16(b.x); t[5] = __float2bfloat16(b.y);
  t[6] = __float2bfloat16(b.z); t[7] = __float2bfloat16(b.w);
  *(float4*)&out[i] = *(float4*)t;
}

// ---------------- pos-embedding projection + L1 norm -> bf16 peT[b][s][q] ----
__global__ __launch_bounds__(64) void pe_kernel(
    const float* __restrict__ pos_embed, const float* __restrict__ pos_w,
    const float* __restrict__ pos_b, __hip_bfloat16* __restrict__ peT)
{
  __shared__ float pw[PP * PP];
  int tid = threadIdx.x;
  for (int i = 0; i < PP; ++i) pw[i * PP + tid] = pos_w[i * PP + tid];
  __syncthreads();
  int s = blockIdx.x * 64 + tid;
  int b = blockIdx.y;
  float acc[PP];
#pragma unroll
  for (int q = 0; q < PP; ++q) acc[q] = pos_b[q];
  for (int p = 0; p < PP; ++p) {
    float x = pos_embed[(size_t)(b * PP + p) * S_LEN + s];
#pragma unroll
    for (int q = 0; q < PP; ++q) acc[q] += pw[q * PP + p] * x;
  }
  float l1 = 0.f;
#pragma unroll
  for (int q = 0; q < PP; ++q) l1 += fabsf(acc[q]);
  float inv = 1.f / fmaxf(l1, 1e-12f);
  __hip_bfloat16 tmp[PP];
#pragma unroll
  for (int q = 0; q < PP; ++q) tmp[q] = __float2bfloat16(acc[q] * inv);
  float4* dst = (float4*)&peT[((size_t)b * S_LEN + s) * PP];
#pragma unroll
  for (int i = 0; i < 8; ++i) dst[i] = ((float4*)tmp)[i];
}

// ---------------- bf16 MFMA GEMM: C[M,N] = A[M,K] @ W[N,K]^T + bias ----------
// 2x2 wave grid, per-wave WRx WC 16x16 frags => tile (32*WR) x (32*WC), BK=64.
template <int WR, int WC>
__global__ __launch_bounds__(256) void gemm_bf16(
    const __hip_bfloat16* __restrict__ A, const __hip_bfloat16* __restrict__ W,
    const float* __restrict__ bias, float* __restrict__ Cf,
    __hip_bfloat16* __restrict__ Cb, int M, int N, int K, int relu, int qkscale,
    long strideA, long strideW, long strideC)
{
  constexpr int BM = 2 * WR * 16;
  constexpr int BN = 2 * WC * 16;
  __shared__ __bf16 As[BM * 64];
  __shared__ __bf16 Bs[BN * 64];
  A += (size_t)blockIdx.z * strideA;
  W += (size_t)blockIdx.z * strideW;
  int tid = threadIdx.x;
  int bm = blockIdx.y * BM;
  int bn = blockIdx.x * BN;
  int wave = tid >> 6, lane = tid & 63;
  int wm = (wave & 1) * (WR * 16), wn = (wave >> 1) * (WC * 16);
  int srow = tid >> 3, scb = tid & 7;
  int gcb = scb ^ (srow & 7);
  const __hip_bfloat16* Ap = A + (size_t)(bm + srow) * K + gcb * 8;
  const __hip_bfloat16* Wp = W + (size_t)(bn + srow) * K + gcb * 8;
  __bf16* AsBase = As + tid * 8;
  __bf16* BsBase = Bs + tid * 8;
  int r15 = lane & 15, quad = lane >> 4;

  floatx4 acc[WR * WC];
#pragma unroll
  for (int i = 0; i < WR * WC; ++i) acc[i] = (floatx4){0.f, 0.f, 0.f, 0.f};

  for (int k0 = 0; k0 < K; k0 += 64) {
    __syncthreads();
#pragma unroll
    for (int io = 0; io < BM / 32; ++io)
      load_lds16(Ap + (size_t)(32 * io) * K + k0, AsBase + io * 2048);
#pragma unroll
    for (int io = 0; io < BN / 32; ++io)
      load_lds16(Wp + (size_t)(32 * io) * K + k0, BsBase + io * 2048);
    __syncthreads();
#pragma unroll
    for (int kc = 0; kc < 2; ++kc) {
      bf16x8 af[WR], bfv[WC];
      int kb = kc * 4 + quad;
#pragma unroll
      for (int i = 0; i < WR; ++i) {
        int rowa = wm + i * 16 + r15;
        af[i] = *(const bf16x8*)&As[rowa * 64 + (kb ^ (rowa & 7)) * 8];
      }
#pragma unroll
      for (int j = 0; j < WC; ++j) {
        int rowb = wn + j * 16 + r15;
        bfv[j] = *(const bf16x8*)&Bs[rowb * 64 + (kb ^ (rowb & 7)) * 8];
      }
#pragma unroll
      for (int i = 0; i < WR; ++i)
#pragma unroll
        for (int j = 0; j < WC; ++j)
          acc[i * WC + j] = __builtin_amdgcn_mfma_f32_16x16x32_bf16(
              af[i], bfv[j], acc[i * WC + j], 0, 0, 0);
    }
  }
  int crow0 = bm + wm + quad * 4;
  int ccol0 = bn + wn + r15;
  float* CfB = Cf ? Cf + (size_t)blockIdx.z * strideC : nullptr;
  __hip_bfloat16* CbB = Cb ? Cb + (size_t)blockIdx.z * strideC : nullptr;
#pragma unroll
  for (int j = 0; j < WC; ++j) {
    int col = ccol0 + j * 16;
    float bv = bias ? bias[col] : 0.f;
    float scale = (qkscale && col < EMB) ? 0.125f : 1.f;
#pragma unroll
    for (int i = 0; i < WR; ++i) {
#pragma unroll
      for (int r = 0; r < 4; ++r) {
        int row = crow0 + i * 16 + r;
        float v = (acc[i * WC + j][r] + bv) * scale;
        if (relu) v = fmaxf(v, 0.f);
        if (CfB) CfB[(size_t)row * N + col] = v;
        if (CbB) CbB[(size_t)row * N + col] = __float2bfloat16(v);
      }
    }
  }
}

// ---------------- transpose V: vT[b, c, t] = qkv_bf[t*B+b, 2E + c] ----------
__global__ __launch_bounds__(256) void transpose_v(
    const __hip_bfloat16* __restrict__ qkv, __hip_bfloat16* __restrict__ vT)
{
  __shared__ __hip_bfloat16 tile[64][72];
  int c0 = blockIdx.x * 64, t0 = blockIdx.y * 64, b = blockIdx.z;
  int tid = threadIdx.x;
#pragma unroll
  for (int i = 0; i < 2; ++i) {
    int k = tid * 2 + i;
    int row = k >> 3, col = (k & 7) * 8;
    float4 v = *(const float4*)&qkv[((size_t)(t0 + row) * BATCH + b) * E3 + 2 * EMB + c0 + col];
    __hip_bfloat16 tmp[8];
    *(float4*)tmp = v;
#pragma unroll
    for (int j = 0; j < 8; ++j) tile[row][col + j] = tmp[j];
  }
  __syncthreads();
#pragma unroll
  for (int i = 0; i < 2; ++i) {
    int k = tid * 2 + i;
    int crow = k >> 3, tcol = (k & 7) * 8;
    __hip_bfloat16 tmp[8];
#pragma unroll
    for (int j = 0; j < 8; ++j) tmp[j] = tile[tcol + j][crow];
    *(float4*)&vT[((size_t)(b * EMB + c0 + crow)) * S_LEN + t0 + tcol] = *(float4*)tmp;
  }
}

// ---------------- MFMA flash attention, double-buffered K/V ------------------
// block = 64 q-rows x (head h, batch b); 4 waves x 16 q-rows; K-tiles of 64.
// Q pre-scaled by 0.125 in qkv GEMM; pos_sim seeds the QK accumulator.
__global__ __launch_bounds__(256) void attn_mfma(
    const __hip_bfloat16* __restrict__ qkv,   // [S*B][E3] bf16 (q pre-scaled)
    const __hip_bfloat16* __restrict__ vT,    // [B][EMB][S] bf16
    const float* __restrict__ pos_sim,        // [B][S][S] fp32
    __hip_bfloat16* __restrict__ ctx)         // [S*B][EMB] bf16
{
  __shared__ __bf16 Ks[2][4096];   // 16 KB
  __shared__ __bf16 Vs[2][4096];   // 16 KB
  __shared__ __bf16 Ps[4096];      // 8 KB: Q staging pre-loop, then per-wave P
  int tid = threadIdx.x;
  int q0 = blockIdx.x * 64, h = blockIdx.y, b = blockIdx.z;
  int w = tid >> 6, lane = tid & 63, quad = lane >> 4, r15 = lane & 15;
  int srow = tid >> 3, scb = tid & 7;

  const __hip_bfloat16* kbase = qkv + EMB + (size_t)h * DH;
  const __hip_bfloat16* vbase = vT + ((size_t)b * EMB + h * DH) * S_LEN;

  // ---- stage Q (into Ps) + first K/V tile ----
  {
    const __hip_bfloat16* qbase = qkv + (size_t)h * DH;
#pragma unroll
    for (int i = 0; i < 2; ++i) {
      int row = i * 32 + srow;
      int gcb = scb ^ (row & 7);
      load_lds16(qbase + ((size_t)(q0 + row) * BATCH + b) * E3 + gcb * 8,
                 Ps + i * 2048 + tid * 8);
      load_lds16(kbase + ((size_t)row * BATCH + b) * E3 + gcb * 8,
                 Ks[0] + i * 2048 + tid * 8);
      load_lds16(vbase + (size_t)row * S_LEN + gcb * 8,
                 Vs[0] + i * 2048 + tid * 8);
    }
  }
  __syncthreads();
  bf16x8 qa[2];
  {
    int row = w * 16 + r15;
#pragma unroll
    for (int kc = 0; kc < 2; ++kc)
      qa[kc] = *(const bf16x8*)&Ps[row * 64 + ((kc * 4 + quad) ^ (r15 & 7)) * 8];
  }
  __syncthreads();   // all waves done reading Q before Ps reuse

  floatx4 of[4];
#pragma unroll
  for (int j = 0; j < 4; ++j) of[j] = (floatx4){0.f, 0.f, 0.f, 0.f};
  float m_run[4], l_run[4];
#pragma unroll
  for (int r = 0; r < 4; ++r) { m_run[r] = -1e30f; l_run[r] = 0.f; }

  const float* psbase =
      pos_sim + ((size_t)(b * S_LEN + q0 + w * 16 + quad * 4)) * S_LEN + r15;
  __bf16* pw = Ps + w * 1024;

  float ps[16];
#pragma unroll
  for (int j = 0; j < 4; ++j)
#pragma unroll
    for (int r = 0; r < 4; ++r)
      ps[j * 4 + r] = psbase[(size_t)r * S_LEN + j * 16];

  for (int kt = 0; kt < 32; ++kt) {
    int cur = kt & 1;
    // ---- issue staging of next tile into the other buffer (no barrier) ----
    if (kt < 31) {
      int tn = (kt + 1) * 64;
      int nb = cur ^ 1;
#pragma unroll
      for (int i = 0; i < 2; ++i) {
        int row = i * 32 + srow;
        int gcb = scb ^ (row & 7);
        load_lds16(kbase + ((size_t)(tn + row) * BATCH + b) * E3 + gcb * 8,
                   Ks[nb] + i * 2048 + tid * 8);
        // V^T: row is the channel index, tn offsets the t (key) dimension.
        load_lds16(vbase + (size_t)row * S_LEN + tn + gcb * 8,
                   Vs[nb] + i * 2048 + tid * 8);
      }
    }
    // ---- prefetch next pos_sim tile into regs ----
    float psn[16];
    if (kt < 31) {
#pragma unroll
      for (int j = 0; j < 4; ++j)
#pragma unroll
        for (int r = 0; r < 4; ++r)
          psn[j * 4 + r] = psbase[(size_t)r * S_LEN + (kt + 1) * 64 + j * 16];
    }

    // ---- S = Q K^T + pos_sim (seeded accumulator) ----
    floatx4 sf[4];
#pragma unroll
    for (int j = 0; j < 4; ++j) {
      sf[j] = (floatx4){ps[j * 4 + 0], ps[j * 4 + 1], ps[j * 4 + 2], ps[j * 4 + 3]};
      int rowk = j * 16 + r15;
      bf16x8 kb0 = *(const bf16x8*)&Ks[cur][rowk * 64 + ((quad) ^ (r15 & 7)) * 8];
      bf16x8 kb1 = *(const bf16x8*)&Ks[cur][rowk * 64 + ((4 + quad) ^ (r15 & 7)) * 8];
      sf[j] = __builtin_amdgcn_mfma_f32_16x16x32_bf16(qa[0], kb0, sf[j], 0, 0, 0);
      sf[j] = __builtin_amdgcn_mfma_f32_16x16x32_bf16(qa[1], kb1, sf[j], 0, 0, 0);
    }

    // ---- online softmax (rows = quad*4+r, reduce over 16 lanes) ----
    float mnew[4], alpha[4];
#pragma unroll
    for (int r = 0; r < 4; ++r) {
      float v = fmaxf(fmaxf(sf[0][r], sf[1][r]), fmaxf(sf[2][r], sf[3][r]));
#pragma unroll
      for (int mask = 1; mask <= 8; mask <<= 1)
        v = fmaxf(v, __shfl_xor(v, mask, 64));
      mnew[r] = fmaxf(m_run[r], v);
      alpha[r] = __expf(m_run[r] - mnew[r]);
      m_run[r] = mnew[r];
    }
#pragma unroll
    for (int j = 0; j < 4; ++j)
#pragma unroll
      for (int r = 0; r < 4; ++r)
        sf[j][r] = __expf(sf[j][r] - mnew[r]);
#pragma unroll
    for (int r = 0; r < 4; ++r) {
      float v = sf[0][r] + sf[1][r] + sf[2][r] + sf[3][r];
#pragma unroll
      for (int mask = 1; mask <= 8; mask <<= 1)
        v += __shfl_xor(v, mask, 64);
      l_run[r] = l_run[r] * alpha[r] + v;
    }
#pragma unroll
    for (int jd = 0; jd < 4; ++jd)
#pragma unroll
      for (int r = 0; r < 4; ++r)
        of[jd][r] *= alpha[r];

    // ---- P (bf16) C-layout -> A-layout via per-wave LDS chunk ----
#pragma unroll
    for (int j = 0; j < 4; ++j) {
      int cb = j * 2 + (r15 >> 3);
#pragma unroll
      for (int r = 0; r < 4; ++r) {
        int row = quad * 4 + r;
        pw[row * 64 + ((cb ^ (row & 7)) * 8) + (r15 & 7)] = (__bf16)sf[j][r];
      }
    }
    __asm__ volatile("s_waitcnt lgkmcnt(0)" ::: "memory");
    bf16x8 pa0 = *(const bf16x8*)&pw[r15 * 64 + ((quad) ^ (r15 & 7)) * 8];
    bf16x8 pa1 = *(const bf16x8*)&pw[r15 * 64 + ((4 + quad) ^ (r15 & 7)) * 8];

    // ---- O += P V ----
#pragma unroll
    for (int jd = 0; jd < 4; ++jd) {
      int rowd = jd * 16 + r15;
      bf16x8 vb0 = *(const bf16x8*)&Vs[cur][rowd * 64 + ((quad) ^ (r15 & 7)) * 8];
      bf16x8 vb1 = *(const bf16x8*)&Vs[cur][rowd * 64 + ((4 + quad) ^ (r15 & 7)) * 8];
      of[jd] = __builtin_amdgcn_mfma_f32_16x16x32_bf16(pa0, vb0, of[jd], 0, 0, 0);
      of[jd] = __builtin_amdgcn_mfma_f32_16x16x32_bf16(pa1, vb1, of[jd], 0, 0, 0);
    }

    if (kt < 31) {
#pragma unroll
      for (int i2 = 0; i2 < 16; ++i2) ps[i2] = psn[i2];
    }
    __syncthreads();   // waves done with bufs[cur]; next-tile staging drained
  }

  // ---- epilogue: O / l ----
#pragma unroll
  for (int r = 0; r < 4; ++r) {
    float inv = 1.f / l_run[r];
    int qrow = q0 + w * 16 + quad * 4 + r;
    __hip_bfloat16* crow = ctx + ((size_t)qrow * BATCH + b) * EMB + h * DH + r15;
#pragma unroll
    for (int jd = 0; jd < 4; ++jd)
      crow[jd * 16] = __float2bfloat16(of[jd][r] * inv);
  }
}

// ---------------- layernorm(x1+x2)*g + b, fp32 out + optional bf16 out -------
__global__ __launch_bounds__(256) void ln_kernel(
    const float* __restrict__ x1, const float* __restrict__ x2,
    const float* __restrict__ g, const float* __restrict__ bb,
    float* __restrict__ out, __hip_bfloat16* __restrict__ out_bf)
{
  int row = blockIdx.x;
  int tid = threadIdx.x;
  const float* p1 = x1 + (size_t)row * EMB;
  const float* p2 = x2 + (size_t)row * EMB;
  float4 v1 = *(const float4*)&p1[tid * 4];
  float4 v2 = *(const float4*)&p2[tid * 4];
  float x[4] = {v1.x + v2.x, v1.y + v2.y, v1.z + v2.z, v1.w + v2.w};
  float s = x[0] + x[1] + x[2] + x[3];
  float s2 = x[0] * x[0] + x[1] * x[1] + x[2] * x[2] + x[3] * x[3];
#pragma unroll
  for (int off = 32; off >= 1; off >>= 1) {
    s  += __shfl_xor(s, off, 64);
    s2 += __shfl_xor(s2, off, 64);
  }
  __shared__ float ws1[4], ws2[4];
  int wid = tid >> 6, lane = tid & 63;
  if (lane == 0) { ws1[wid] = s; ws2[wid] = s2; }
  __syncthreads();
  s  = ws1[0] + ws1[1] + ws1[2] + ws1[3];
  s2 = ws2[0] + ws2[1] + ws2[2] + ws2[3];
  float mean = s * (1.f / EMB);
  float var  = s2 * (1.f / EMB) - mean * mean;
  float inv  = rsqrtf(var + 1e-5f);
  float4 gv = *(const float4*)&g[tid * 4];
  float4 bv = *(const float4*)&bb[tid * 4];
  float4 o;
  o.x = (x[0] - mean) * inv * gv.x + bv.x;
  o.y = (x[1] - mean) * inv * gv.y + bv.y;
  o.z = (x[2] - mean) * inv * gv.z + bv.z;
  o.w = (x[3] - mean) * inv * gv.w + bv.w;
  *(float4*)&out[(size_t)row * EMB + tid * 4] = o;
  if (out_bf) {
    __hip_bfloat16 t[4];
    t[0] = __float2bfloat16(o.x); t[1] = __float2bfloat16(o.y);
    t[2] = __float2bfloat16(o.z); t[3] = __float2bfloat16(o.w);
    *(float2*)&out_bf[(size_t)row * EMB + tid * 4] = *(float2*)t;
  }
}

extern "C" void kernel_launch(void* const* d_in, const int* in_sizes, int n_in,
                              void* d_out, int out_size, void* d_ws, size_t ws_size,
                              hipStream_t stream)
{
  const float* src       = (const float*)d_in[0];
  const float* pos_embed = (const float*)d_in[1];
  const float* in_proj_w = (const float*)d_in[2];
  const float* in_proj_b = (const float*)d_in[3];
  const float* out_w     = (const float*)d_in[4];
  const float* out_b     = (const float*)d_in[5];
  const float* lin1_w    = (const float*)d_in[6];
  const float* lin1_b    = (const float*)d_in[7];
  const float* lin2_w    = (const float*)d_in[8];
  const float* lin2_b    = (const float*)d_in[9];
  const float* ln1_g     = (const float*)d_in[10];
  const float* ln1_b     = (const float*)d_in[11];
  const float* ln2_g     = (const float*)d_in[12];
  const float* ln2_b     = (const float*)d_in[13];
  const float* pos_w     = (const float*)d_in[14];
  const float* pos_b     = (const float*)d_in[15];
  float* out = (float*)d_out;
  float* ws  = (float*)d_ws;

  // ---- workspace layout (float units), peak 31,588,352 floats ≈ 126 MB ----
  __hip_bfloat16* peT    = (__hip_bfloat16*)ws;                // 262,144 el -> 131,072 fl
  float* pos_sim         = ws + 131072;                        // 8,388,608 -> 8,519,680
  __hip_bfloat16* qkv_bf = (__hip_bfloat16*)(ws + 8519680);    // 12,582,912 el -> 14,811,136
  __hip_bfloat16* vT_bf  = (__hip_bfloat16*)(ws + 14811136);   // 4,194,304 el -> 16,908,288
  __hip_bfloat16* src_bf = (__hip_bfloat16*)(ws + 16908288);   // 4,194,304 el -> 19,005,440
  __hip_bfloat16* inw_bf  = (__hip_bfloat16*)(ws + 19005440);  // 3,145,728 el -> 20,578,304
  __hip_bfloat16* outw_bf = (__hip_bfloat16*)(ws + 20578304);  // 1,048,576 el -> 21,102,592
  __hip_bfloat16* ctx_bf = (__hip_bfloat16*)(ws + 21102592);   // 4,194,304 el -> 23,199,744
  __hip_bfloat16* l1w_bf = (__hip_bfloat16*)(ws + 23199744);   // 4,194,304 el -> 25,296,896
  __hip_bfloat16* l2w_bf = (__hip_bfloat16*)(ws + 25296896);   // 4,194,304 el -> 27,394,048
  float* proj            = ws + 27394048;                      // 4,194,304 -> 31,588,352
  // phase-2 reuse (peT/pos_sim/qkv/vT dead after attn):
  __hip_bfloat16* x_bf   = (__hip_bfloat16*)ws;                // 4,194,304 el -> 2,097,152 fl
  float* xbuf            = ws + 2097152;                       // 4,194,304 -> 6,291,456
  __hip_bfloat16* h1_bf  = (__hip_bfloat16*)(ws + 6291456);    // 16,777,216 el -> 14,680,064 fl

  const int M = S_LEN * BATCH;  // 4096 rows, row = s*B + b

  cvt_kernel<<<4194304 / 2048, 256, 0, stream>>>(src, src_bf, 4194304);
  cvt_kernel<<<3145728 / 2048, 256, 0, stream>>>(in_proj_w, inw_bf, 3145728);
  cvt_kernel<<<1048576 / 2048, 256, 0, stream>>>(out_w, outw_bf, 1048576);
  cvt_kernel<<<4194304 / 2048, 256, 0, stream>>>(lin1_w, l1w_bf, 4194304);
  cvt_kernel<<<4194304 / 2048, 256, 0, stream>>>(lin2_w, l2w_bf, 4194304);
  pe_kernel<<<dim3(S_LEN / 64, BATCH), 64, 0, stream>>>(pos_embed, pos_w, pos_b, peT);
  // pos_sim[b] = peT[b] @ peT[b]^T  (M=N=2048, K=64), fp32 out
  gemm_bf16<4, 4><<<dim3(2048 / 128, 2048 / 128, BATCH), 256, 0, stream>>>(
      peT, peT, nullptr, pos_sim, nullptr, 2048, 2048, 64, 0, 0,
      (long)2048 * 64, (long)2048 * 64, (long)2048 * 2048);
  // qkv = src @ in_proj_w^T + b, q-cols pre-scaled by 0.125
  gemm_bf16<4, 4><<<dim3(E3 / 128, M / 128, 1), 256, 0, stream>>>(
      src_bf, inw_bf, in_proj_b, nullptr, qkv_bf, M, E3, EMB, 0, 1, 0, 0, 0);
  transpose_v<<<dim3(EMB / 64, S_LEN / 64, BATCH), 256, 0, stream>>>(qkv_bf, vT_bf);
  attn_mfma<<<dim3(S_LEN / 64, NH, BATCH), 256, 0, stream>>>(
      qkv_bf, vT_bf, pos_sim, ctx_bf);
  // attn_out = ctx @ out_w^T + b   (N=1024: 64x128 tiles -> 512 blocks)
  gemm_bf16<2, 4><<<dim3(EMB / 128, M / 64, 1), 256, 0, stream>>>(
      ctx_bf, outw_bf, out_b, proj, nullptr, M, EMB, EMB, 0, 0, 0, 0, 0);
  ln_kernel<<<dim3(M), 256, 0, stream>>>(src, proj, ln1_g, ln1_b, xbuf, x_bf);
  gemm_bf16<4, 4><<<dim3(FF / 128, M / 128, 1), 256, 0, stream>>>(
      x_bf, l1w_bf, lin1_b, nullptr, h1_bf, M, FF, EMB, 1, 0, 0, 0, 0);
  gemm_bf16<2, 4><<<dim3(EMB / 128, M / 64, 1), 256, 0, stream>>>(
      h1_bf, l2w_bf, lin2_b, proj, nullptr, M, EMB, FF, 0, 0, 0, 0, 0);
  ln_kernel<<<dim3(M), 256, 0, stream>>>(xbuf, proj, ln2_g, ln2_b, out, nullptr);
}

// Round 6
// 451.172 us; speedup vs baseline: 5.0948x; 1.1416x over previous
//
#include <hip/hip_runtime.h>
#include <hip/hip_bf16.h>
#include <math.h>

#define S_LEN 2048
#define BATCH 2
#define EMB   1024
#define NH    16
#define DH    64
#define E3    3072
#define FF    4096
#define PP    64

typedef __bf16 bf16x8 __attribute__((ext_vector_type(8)));
typedef float  floatx4 __attribute__((ext_vector_type(4)));

__device__ __forceinline__ void load_lds16(const void* g, void* l) {
  __builtin_amdgcn_global_load_lds(
      (const __attribute__((address_space(1))) void*)g,
      (__attribute__((address_space(3))) void*)l, 16, 0, 0);
}

// ---------------- fp32 -> bf16 convert (8 elems/thread) ----------------
__global__ __launch_bounds__(256) void cvt_kernel(
    const float* __restrict__ in, __hip_bfloat16* __restrict__ out, int n)
{
  int i = (blockIdx.x * 256 + threadIdx.x) * 8;
  if (i >= n) return;
  float4 a = *(const float4*)&in[i];
  float4 b = *(const float4*)&in[i + 4];
  __hip_bfloat16 t[8];
  t[0] = __float2bfloat16(a.x); t[1] = __float2bfloat16(a.y);
  t[2] = __float2bfloat16(a.z); t[3] = __float2bfloat16(a.w);
  t[4] = __float2bfloat16(b.x); t[5] = __float2bfloat16(b.y);
  t[6] = __float2bfloat16(b.z); t[7] = __float2bfloat16(b.w);
  *(float4*)&out[i] = *(float4*)t;
}

// ---------------- pos-embedding projection + L1 norm -> bf16 peT[b][s][q] ----
__global__ __launch_bounds__(64) void pe_kernel(
    const float* __restrict__ pos_embed, const float* __restrict__ pos_w,
    const float* __restrict__ pos_b, __hip_bfloat16* __restrict__ peT)
{
  __shared__ float pw[PP * PP];
  int tid = threadIdx.x;
  for (int i = 0; i < PP; ++i) pw[i * PP + tid] = pos_w[i * PP + tid];
  __syncthreads();
  int s = blockIdx.x * 64 + tid;
  int b = blockIdx.y;
  float acc[PP];
#pragma unroll
  for (int q = 0; q < PP; ++q) acc[q] = pos_b[q];
  for (int p = 0; p < PP; ++p) {
    float x = pos_embed[(size_t)(b * PP + p) * S_LEN + s];
#pragma unroll
    for (int q = 0; q < PP; ++q) acc[q] += pw[q * PP + p] * x;
  }
  float l1 = 0.f;
#pragma unroll
  for (int q = 0; q < PP; ++q) l1 += fabsf(acc[q]);
  float inv = 1.f / fmaxf(l1, 1e-12f);
  __hip_bfloat16 tmp[PP];
#pragma unroll
  for (int q = 0; q < PP; ++q) tmp[q] = __float2bfloat16(acc[q] * inv);
  float4* dst = (float4*)&peT[((size_t)b * S_LEN + s) * PP];
#pragma unroll
  for (int i = 0; i < 8; ++i) dst[i] = ((float4*)tmp)[i];
}

// ---------------- bf16 MFMA GEMM: C[M,N] = A[M,K] @ W[N,K]^T + bias ----------
// 2x2 wave grid, per-wave WRx WC 16x16 frags => tile (32*WR) x (32*WC), BK=64.
template <int WR, int WC>
__global__ __launch_bounds__(256) void gemm_bf16(
    const __hip_bfloat16* __restrict__ A, const __hip_bfloat16* __restrict__ W,
    const float* __restrict__ bias, float* __restrict__ Cf,
    __hip_bfloat16* __restrict__ Cb, int M, int N, int K, int relu, int qkscale,
    long strideA, long strideW, long strideC)
{
  constexpr int BM = 2 * WR * 16;
  constexpr int BN = 2 * WC * 16;
  __shared__ __bf16 As[BM * 64];
  __shared__ __bf16 Bs[BN * 64];
  A += (size_t)blockIdx.z * strideA;
  W += (size_t)blockIdx.z * strideW;
  int tid = threadIdx.x;
  int bm = blockIdx.y * BM;
  int bn = blockIdx.x * BN;
  int wave = tid >> 6, lane = tid & 63;
  int wm = (wave & 1) * (WR * 16), wn = (wave >> 1) * (WC * 16);
  int srow = tid >> 3, scb = tid & 7;
  int gcb = scb ^ (srow & 7);
  const __hip_bfloat16* Ap = A + (size_t)(bm + srow) * K + gcb * 8;
  const __hip_bfloat16* Wp = W + (size_t)(bn + srow) * K + gcb * 8;
  __bf16* AsBase = As + tid * 8;
  __bf16* BsBase = Bs + tid * 8;
  int r15 = lane & 15, quad = lane >> 4;

  floatx4 acc[WR * WC];
#pragma unroll
  for (int i = 0; i < WR * WC; ++i) acc[i] = (floatx4){0.f, 0.f, 0.f, 0.f};

  for (int k0 = 0; k0 < K; k0 += 64) {
    __syncthreads();
#pragma unroll
    for (int io = 0; io < BM / 32; ++io)
      load_lds16(Ap + (size_t)(32 * io) * K + k0, AsBase + io * 2048);
#pragma unroll
    for (int io = 0; io < BN / 32; ++io)
      load_lds16(Wp + (size_t)(32 * io) * K + k0, BsBase + io * 2048);
    __syncthreads();
#pragma unroll
    for (int kc = 0; kc < 2; ++kc) {
      bf16x8 af[WR], bfv[WC];
      int kb = kc * 4 + quad;
#pragma unroll
      for (int i = 0; i < WR; ++i) {
        int rowa = wm + i * 16 + r15;
        af[i] = *(const bf16x8*)&As[rowa * 64 + (kb ^ (rowa & 7)) * 8];
      }
#pragma unroll
      for (int j = 0; j < WC; ++j) {
        int rowb = wn + j * 16 + r15;
        bfv[j] = *(const bf16x8*)&Bs[rowb * 64 + (kb ^ (rowb & 7)) * 8];
      }
#pragma unroll
      for (int i = 0; i < WR; ++i)
#pragma unroll
        for (int j = 0; j < WC; ++j)
          acc[i * WC + j] = __builtin_amdgcn_mfma_f32_16x16x32_bf16(
              af[i], bfv[j], acc[i * WC + j], 0, 0, 0);
    }
  }
  int crow0 = bm + wm + quad * 4;
  int ccol0 = bn + wn + r15;
  float* CfB = Cf ? Cf + (size_t)blockIdx.z * strideC : nullptr;
  __hip_bfloat16* CbB = Cb ? Cb + (size_t)blockIdx.z * strideC : nullptr;
#pragma unroll
  for (int j = 0; j < WC; ++j) {
    int col = ccol0 + j * 16;
    float bv = bias ? bias[col] : 0.f;
    float scale = (qkscale && col < EMB) ? 0.125f : 1.f;
#pragma unroll
    for (int i = 0; i < WR; ++i) {
#pragma unroll
      for (int r = 0; r < 4; ++r) {
        int row = crow0 + i * 16 + r;
        float v = (acc[i * WC + j][r] + bv) * scale;
        if (relu) v = fmaxf(v, 0.f);
        if (CfB) CfB[(size_t)row * N + col] = v;
        if (CbB) CbB[(size_t)row * N + col] = __float2bfloat16(v);
      }
    }
  }
}

// ---------------- transpose V: vT[b, c, t] = qkv_bf[t*B+b, 2E + c] ----------
__global__ __launch_bounds__(256) void transpose_v(
    const __hip_bfloat16* __restrict__ qkv, __hip_bfloat16* __restrict__ vT)
{
  __shared__ __hip_bfloat16 tile[64][72];
  int c0 = blockIdx.x * 64, t0 = blockIdx.y * 64, b = blockIdx.z;
  int tid = threadIdx.x;
#pragma unroll
  for (int i = 0; i < 2; ++i) {
    int k = tid * 2 + i;
    int row = k >> 3, col = (k & 7) * 8;
    float4 v = *(const float4*)&qkv[((size_t)(t0 + row) * BATCH + b) * E3 + 2 * EMB + c0 + col];
    __hip_bfloat16 tmp[8];
    *(float4*)tmp = v;
#pragma unroll
    for (int j = 0; j < 8; ++j) tile[row][col + j] = tmp[j];
  }
  __syncthreads();
#pragma unroll
  for (int i = 0; i < 2; ++i) {
    int k = tid * 2 + i;
    int crow = k >> 3, tcol = (k & 7) * 8;
    __hip_bfloat16 tmp[8];
#pragma unroll
    for (int j = 0; j < 8; ++j) tmp[j] = tile[tcol + j][crow];
    *(float4*)&vT[((size_t)(b * EMB + c0 + crow)) * S_LEN + t0 + tcol] = *(float4*)tmp;
  }
}

// ---------------- MFMA flash attention, S^T form, no-max softmax -------------
// block = 128 q x (h, b); 4 waves x 32 q (2 q-blocks of 16); K-tiles of 64.
// S^T = K Q^T  (C-layout: col=query=r15, row=key=quad*4+reg) so pos_sim seeds
// are float4 loads and P^T feeds PV as the B operand after a cheap b64/b128
// LDS round trip. exp() without max subtraction (scores bounded; clamp 60);
// per-lane partial row-sums reduced once at the epilogue.
__global__ __launch_bounds__(256) void attn_mfma(
    const __hip_bfloat16* __restrict__ qkv,   // [S*B][E3] bf16 (q pre-scaled)
    const __hip_bfloat16* __restrict__ vT,    // [B][EMB][S] bf16
    const float* __restrict__ pos_sim,        // [B][S][S] fp32
    __hip_bfloat16* __restrict__ ctx)         // [S*B][EMB] bf16
{
  __shared__ __bf16 Ks[2][4096];   // 16 KB  [key][d] swizzled
  __shared__ __bf16 Vs[2][4096];   // 16 KB  [d][t]  swizzled
  __shared__ __bf16 Ps[8192];      // 16 KB  per (wave,qb): [query][key] swizzled
  int tid = threadIdx.x;
  int q0 = blockIdx.x * 128, h = blockIdx.y, b = blockIdx.z;
  int w = tid >> 6, lane = tid & 63, quad = lane >> 4, r15 = lane & 15;
  int srow = tid >> 3, scb = tid & 7;
  int x7 = r15 & 7;

  const __hip_bfloat16* kbase = qkv + EMB + (size_t)h * DH;
  const __hip_bfloat16* vbase = vT + ((size_t)b * EMB + h * DH) * S_LEN;

  // ---- Q fragments straight to registers (B-operand layout) ----
  bf16x8 qa[2][2];
#pragma unroll
  for (int qb = 0; qb < 2; ++qb)
#pragma unroll
    for (int kc = 0; kc < 2; ++kc)
      qa[qb][kc] = *(const bf16x8*)&qkv[
          ((size_t)(q0 + w * 32 + qb * 16 + r15) * BATCH + b) * E3 +
          h * DH + kc * 32 + quad * 8];

  // ---- stage first K/V tile ----
#pragma unroll
  for (int i = 0; i < 2; ++i) {
    int row = i * 32 + srow;
    int gcb = scb ^ (row & 7);
    load_lds16(kbase + ((size_t)row * BATCH + b) * E3 + gcb * 8,
               Ks[0] + i * 2048 + tid * 8);
    load_lds16(vbase + (size_t)row * S_LEN + gcb * 8,
               Vs[0] + i * 2048 + tid * 8);
  }
  __syncthreads();

  floatx4 of[2][4];
#pragma unroll
  for (int qb = 0; qb < 2; ++qb)
#pragma unroll
    for (int j = 0; j < 4; ++j) of[qb][j] = (floatx4){0.f, 0.f, 0.f, 0.f};
  float lp[2] = {0.f, 0.f};

  const float* psb[2];
#pragma unroll
  for (int qb = 0; qb < 2; ++qb)
    psb[qb] = pos_sim + ((size_t)(b * S_LEN + q0 + w * 32 + qb * 16 + r15)) * S_LEN
              + quad * 4;
  __bf16* pw0 = Ps + (w * 2 + 0) * 1024;
  __bf16* pw1 = Ps + (w * 2 + 1) * 1024;

  for (int kt = 0; kt < 32; ++kt) {
    int cur = kt & 1;
    int t0 = kt * 64;
    // ---- pos_sim seeds FIRST (so their vmcnt wait leaves staging in flight) --
    floatx4 sf[2][4];
#pragma unroll
    for (int qb = 0; qb < 2; ++qb)
#pragma unroll
      for (int j = 0; j < 4; ++j)
        sf[qb][j] = *(const floatx4*)(psb[qb] + t0 + j * 16);
    // ---- stage next K/V tile into the other buffer ----
    if (kt < 31) {
      int tn = t0 + 64;
      int nb = cur ^ 1;
#pragma unroll
      for (int i = 0; i < 2; ++i) {
        int row = i * 32 + srow;
        int gcb = scb ^ (row & 7);
        load_lds16(kbase + ((size_t)(tn + row) * BATCH + b) * E3 + gcb * 8,
                   Ks[nb] + i * 2048 + tid * 8);
        // V^T: row = channel, tn offsets the key (t) dimension.
        load_lds16(vbase + (size_t)row * S_LEN + tn + gcb * 8,
                   Vs[nb] + i * 2048 + tid * 8);
      }
    }

    // ---- S^T = K Q^T + pos_sim (A = K rows=keys, B = Q^T cols=queries) ----
#pragma unroll
    for (int j = 0; j < 4; ++j) {
      int rowk = j * 16 + r15;
      bf16x8 kf0 = *(const bf16x8*)&Ks[cur][rowk * 64 + (quad ^ (rowk & 7)) * 8];
      bf16x8 kf1 = *(const bf16x8*)&Ks[cur][rowk * 64 + ((4 + quad) ^ (rowk & 7)) * 8];
#pragma unroll
      for (int qb = 0; qb < 2; ++qb) {
        sf[qb][j] = __builtin_amdgcn_mfma_f32_16x16x32_bf16(kf0, qa[qb][0], sf[qb][j], 0, 0, 0);
        sf[qb][j] = __builtin_amdgcn_mfma_f32_16x16x32_bf16(kf1, qa[qb][1], sf[qb][j], 0, 0, 0);
      }
    }

    // ---- exp (no max), accumulate per-lane l, pack P^T -> LDS ----
#pragma unroll
    for (int qb = 0; qb < 2; ++qb) {
      __bf16* pwq = qb ? pw1 : pw0;
#pragma unroll
      for (int j = 0; j < 4; ++j) {
        float e0 = __expf(fminf(sf[qb][j][0], 60.f));
        float e1 = __expf(fminf(sf[qb][j][1], 60.f));
        float e2 = __expf(fminf(sf[qb][j][2], 60.f));
        float e3 = __expf(fminf(sf[qb][j][3], 60.f));
        lp[qb] += (e0 + e1) + (e2 + e3);
        __hip_bfloat16 t4[4];
        t4[0] = __float2bfloat16(e0); t4[1] = __float2bfloat16(e1);
        t4[2] = __float2bfloat16(e2); t4[3] = __float2bfloat16(e3);
        // keys j*16+quad*4+(0..3), query r15; block = key>>3 = j*2+(quad>>1)
        int addr = r15 * 64 + (((j * 2 + (quad >> 1)) ^ x7) * 8) + (quad & 1) * 4;
        *(float2*)&pwq[addr] = *(float2*)t4;
      }
    }
    __asm__ volatile("s_waitcnt lgkmcnt(0)" ::: "memory");

    // ---- O^T += V^T P^T  (A = V^T rows=d, B = P^T cols=queries) ----
    bf16x8 pb00 = *(const bf16x8*)&pw0[r15 * 64 + ((quad ^ x7) * 8)];
    bf16x8 pb01 = *(const bf16x8*)&pw0[r15 * 64 + (((4 + quad) ^ x7) * 8)];
    bf16x8 pb10 = *(const bf16x8*)&pw1[r15 * 64 + ((quad ^ x7) * 8)];
    bf16x8 pb11 = *(const bf16x8*)&pw1[r15 * 64 + (((4 + quad) ^ x7) * 8)];
#pragma unroll
    for (int jd = 0; jd < 4; ++jd) {
      int rowd = jd * 16 + r15;
      bf16x8 vb0 = *(const bf16x8*)&Vs[cur][rowd * 64 + (quad ^ (rowd & 7)) * 8];
      bf16x8 vb1 = *(const bf16x8*)&Vs[cur][rowd * 64 + ((4 + quad) ^ (rowd & 7)) * 8];
      of[0][jd] = __builtin_amdgcn_mfma_f32_16x16x32_bf16(vb0, pb00, of[0][jd], 0, 0, 0);
      of[0][jd] = __builtin_amdgcn_mfma_f32_16x16x32_bf16(vb1, pb01, of[0][jd], 0, 0, 0);
      of[1][jd] = __builtin_amdgcn_mfma_f32_16x16x32_bf16(vb0, pb10, of[1][jd], 0, 0, 0);
      of[1][jd] = __builtin_amdgcn_mfma_f32_16x16x32_bf16(vb1, pb11, of[1][jd], 0, 0, 0);
    }
    __syncthreads();   // waves done with bufs[cur]; next-tile staging drained
  }

  // ---- epilogue: reduce l over quads, O^T / l, packed 8B stores ----
#pragma unroll
  for (int qb = 0; qb < 2; ++qb) {
    float l = lp[qb];
    l += __shfl_xor(l, 16, 64);
    l += __shfl_xor(l, 32, 64);
    float inv = 1.f / l;
    size_t rbase = ((size_t)(q0 + w * 32 + qb * 16 + r15) * BATCH + b) * EMB + h * DH;
#pragma unroll
    for (int jd = 0; jd < 4; ++jd) {
      __hip_bfloat16 o4[4];
      o4[0] = __float2bfloat16(of[qb][jd][0] * inv);
      o4[1] = __float2bfloat16(of[qb][jd][1] * inv);
      o4[2] = __float2bfloat16(of[qb][jd][2] * inv);
      o4[3] = __float2bfloat16(of[qb][jd][3] * inv);
      *(float2*)&ctx[rbase + jd * 16 + quad * 4] = *(float2*)o4;
    }
  }
}

// ---------------- layernorm(x1+x2)*g + b, fp32 out + optional bf16 out -------
__global__ __launch_bounds__(256) void ln_kernel(
    const float* __restrict__ x1, const float* __restrict__ x2,
    const float* __restrict__ g, const float* __restrict__ bb,
    float* __restrict__ out, __hip_bfloat16* __restrict__ out_bf)
{
  int row = blockIdx.x;
  int tid = threadIdx.x;
  const float* p1 = x1 + (size_t)row * EMB;
  const float* p2 = x2 + (size_t)row * EMB;
  float4 v1 = *(const float4*)&p1[tid * 4];
  float4 v2 = *(const float4*)&p2[tid * 4];
  float x[4] = {v1.x + v2.x, v1.y + v2.y, v1.z + v2.z, v1.w + v2.w};
  float s = x[0] + x[1] + x[2] + x[3];
  float s2 = x[0] * x[0] + x[1] * x[1] + x[2] * x[2] + x[3] * x[3];
#pragma unroll
  for (int off = 32; off >= 1; off >>= 1) {
    s  += __shfl_xor(s, off, 64);
    s2 += __shfl_xor(s2, off, 64);
  }
  __shared__ float ws1[4], ws2[4];
  int wid = tid >> 6, lane = tid & 63;
  if (lane == 0) { ws1[wid] = s; ws2[wid] = s2; }
  __syncthreads();
  s  = ws1[0] + ws1[1] + ws1[2] + ws1[3];
  s2 = ws2[0] + ws2[1] + ws2[2] + ws2[3];
  float mean = s * (1.f / EMB);
  float var  = s2 * (1.f / EMB) - mean * mean;
  float inv  = rsqrtf(var + 1e-5f);
  float4 gv = *(const float4*)&g[tid * 4];
  float4 bv = *(const float4*)&bb[tid * 4];
  float4 o;
  o.x = (x[0] - mean) * inv * gv.x + bv.x;
  o.y = (x[1] - mean) * inv * gv.y + bv.y;
  o.z = (x[2] - mean) * inv * gv.z + bv.z;
  o.w = (x[3] - mean) * inv * gv.w + bv.w;
  *(float4*)&out[(size_t)row * EMB + tid * 4] = o;
  if (out_bf) {
    __hip_bfloat16 t[4];
    t[0] = __float2bfloat16(o.x); t[1] = __float2bfloat16(o.y);
    t[2] = __float2bfloat16(o.z); t[3] = __float2bfloat16(o.w);
    *(float2*)&out_bf[(size_t)row * EMB + tid * 4] = *(float2*)t;
  }
}

extern "C" void kernel_launch(void* const* d_in, const int* in_sizes, int n_in,
                              void* d_out, int out_size, void* d_ws, size_t ws_size,
                              hipStream_t stream)
{
  const float* src       = (const float*)d_in[0];
  const float* pos_embed = (const float*)d_in[1];
  const float* in_proj_w = (const float*)d_in[2];
  const float* in_proj_b = (const float*)d_in[3];
  const float* out_w     = (const float*)d_in[4];
  const float* out_b     = (const float*)d_in[5];
  const float* lin1_w    = (const float*)d_in[6];
  const float* lin1_b    = (const float*)d_in[7];
  const float* lin2_w    = (const float*)d_in[8];
  const float* lin2_b    = (const float*)d_in[9];
  const float* ln1_g     = (const float*)d_in[10];
  const float* ln1_b     = (const float*)d_in[11];
  const float* ln2_g     = (const float*)d_in[12];
  const float* ln2_b     = (const float*)d_in[13];
  const float* pos_w     = (const float*)d_in[14];
  const float* pos_b     = (const float*)d_in[15];
  float* out = (float*)d_out;
  float* ws  = (float*)d_ws;

  // ---- workspace layout (float units), peak 31,588,352 floats ≈ 126 MB ----
  __hip_bfloat16* peT    = (__hip_bfloat16*)ws;                // 262,144 el -> 131,072 fl
  float* pos_sim         = ws + 131072;                        // 8,388,608 -> 8,519,680
  __hip_bfloat16* qkv_bf = (__hip_bfloat16*)(ws + 8519680);    // 12,582,912 el -> 14,811,136
  __hip_bfloat16* vT_bf  = (__hip_bfloat16*)(ws + 14811136);   // 4,194,304 el -> 16,908,288
  __hip_bfloat16* src_bf = (__hip_bfloat16*)(ws + 16908288);   // 4,194,304 el -> 19,005,440
  __hip_bfloat16* inw_bf  = (__hip_bfloat16*)(ws + 19005440);  // 3,145,728 el -> 20,578,304
  __hip_bfloat16* outw_bf = (__hip_bfloat16*)(ws + 20578304);  // 1,048,576 el -> 21,102,592
  __hip_bfloat16* ctx_bf = (__hip_bfloat16*)(ws + 21102592);   // 4,194,304 el -> 23,199,744
  __hip_bfloat16* l1w_bf = (__hip_bfloat16*)(ws + 23199744);   // 4,194,304 el -> 25,296,896
  __hip_bfloat16* l2w_bf = (__hip_bfloat16*)(ws + 25296896);   // 4,194,304 el -> 27,394,048
  float* proj            = ws + 27394048;                      // 4,194,304 -> 31,588,352
  // phase-2 reuse (peT/pos_sim/qkv/vT dead after attn):
  __hip_bfloat16* x_bf   = (__hip_bfloat16*)ws;                // 4,194,304 el -> 2,097,152 fl
  float* xbuf            = ws + 2097152;                       // 4,194,304 -> 6,291,456
  __hip_bfloat16* h1_bf  = (__hip_bfloat16*)(ws + 6291456);    // 16,777,216 el -> 14,680,064 fl

  const int M = S_LEN * BATCH;  // 4096 rows, row = s*B + b

  cvt_kernel<<<4194304 / 2048, 256, 0, stream>>>(src, src_bf, 4194304);
  cvt_kernel<<<3145728 / 2048, 256, 0, stream>>>(in_proj_w, inw_bf, 3145728);
  cvt_kernel<<<1048576 / 2048, 256, 0, stream>>>(out_w, outw_bf, 1048576);
  cvt_kernel<<<4194304 / 2048, 256, 0, stream>>>(lin1_w, l1w_bf, 4194304);
  cvt_kernel<<<4194304 / 2048, 256, 0, stream>>>(lin2_w, l2w_bf, 4194304);
  pe_kernel<<<dim3(S_LEN / 64, BATCH), 64, 0, stream>>>(pos_embed, pos_w, pos_b, peT);
  // pos_sim[b] = peT[b] @ peT[b]^T  (M=N=2048, K=64), fp32 out
  gemm_bf16<4, 4><<<dim3(2048 / 128, 2048 / 128, BATCH), 256, 0, stream>>>(
      peT, peT, nullptr, pos_sim, nullptr, 2048, 2048, 64, 0, 0,
      (long)2048 * 64, (long)2048 * 64, (long)2048 * 2048);
  // qkv = src @ in_proj_w^T + b, q-cols pre-scaled by 0.125
  gemm_bf16<4, 4><<<dim3(E3 / 128, M / 128, 1), 256, 0, stream>>>(
      src_bf, inw_bf, in_proj_b, nullptr, qkv_bf, M, E3, EMB, 0, 1, 0, 0, 0);
  transpose_v<<<dim3(EMB / 64, S_LEN / 64, BATCH), 256, 0, stream>>>(qkv_bf, vT_bf);
  attn_mfma<<<dim3(S_LEN / 128, NH, BATCH), 256, 0, stream>>>(
      qkv_bf, vT_bf, pos_sim, ctx_bf);
  // attn_out = ctx @ out_w^T + b   (N=1024: 64x128 tiles -> 512 blocks)
  gemm_bf16<2, 4><<<dim3(EMB / 128, M / 64, 1), 256, 0, stream>>>(
      ctx_bf, outw_bf, out_b, proj, nullptr, M, EMB, EMB, 0, 0, 0, 0, 0);
  ln_kernel<<<dim3(M), 256, 0, stream>>>(src, proj, ln1_g, ln1_b, xbuf, x_bf);
  gemm_bf16<4, 4><<<dim3(FF / 128, M / 128, 1), 256, 0, stream>>>(
      x_bf, l1w_bf, lin1_b, nullptr, h1_bf, M, FF, EMB, 1, 0, 0, 0, 0);
  gemm_bf16<2, 4><<<dim3(EMB / 128, M / 64, 1), 256, 0, stream>>>(
      h1_bf, l2w_bf, lin2_b, proj, nullptr, M, EMB, FF, 0, 0, 0, 0, 0);
  ln_kernel<<<dim3(M), 256, 0, stream>>>(xbuf, proj, ln2_g, ln2_b, out, nullptr);
}